// Round 2
// baseline (5489.695 us; speedup 1.0000x reference)
//
#include <hip/hip_runtime.h>

#define N_NODES 100000
#define N_EDGES 1600000
#define C_DIM   128
#define R_TYPES 7
#define T_TYPES 4
#define SEGS    (N_NODES * R_TYPES)          // 700000 (dst,rel) segments

// ---- workspace layout (bytes) — total ~67 MB ----
#define OFF_CNTI   0ull                       // int  cnt[SEGS]            2.8 MB
#define OFF_INV    2800000ull                 // f32  inv[SEGS]            2.8 MB
#define OFF_MISC   5600000ull                 // int  misc[32]
// misc: [0..3]=type counts, [4..7]=type cursors, [8..14]=rel counts,
//       [16..23]=rel starts (+[23]=E), [24..30]=rel cursors
#define OFF_PERM   5600256ull                 // int  perm[PERM_CAP]       0.4 MB
#define PERM_CAP   100288                     // 64 * 1567 (N + per-type pad)
#define N_PERM_BLOCKS 1567
#define OFF_ELIST  6001408ull                 // int2 elist[E] (src,dst)  12.8 MB
#define OFF_XW     18801408ull                // f32  xw[N*128]           51.2 MB
#define WS_NEEDED  70001408ull

// ---------------- counting ----------------
__global__ void count_edges(const int* __restrict__ ei, const int* __restrict__ et,
                            int* __restrict__ cnti, int* __restrict__ misc) {
    int e = blockIdx.x * blockDim.x + threadIdx.x;
    int r = -1;
    if (e < N_EDGES) {
        int d = ei[N_EDGES + e];
        r = et[e];
        atomicAdd(&cnti[d * R_TYPES + r], 1);
    }
    int lane = threadIdx.x & 63;
    for (int rr = 0; rr < R_TYPES; ++rr) {
        unsigned long long m = __ballot(r == rr);
        if (m != 0ull) {
            int leader = __ffsll((unsigned long long)m) - 1;
            if (lane == leader) atomicAdd(&misc[8 + rr], (int)__popcll(m));
        }
    }
}

__global__ void inv_kernel(const int* __restrict__ cnti, float* __restrict__ inv) {
    int i = blockIdx.x * blockDim.x + threadIdx.x;
    if (i < SEGS) inv[i] = 1.0f / (float)max(cnti[i], 1);
}

__global__ void type_count(const int* __restrict__ tnt, int* __restrict__ misc) {
    int n = blockIdx.x * blockDim.x + threadIdx.x;
    int t = (n < N_NODES) ? tnt[n] : -1;
    int lane = threadIdx.x & 63;
    for (int tt = 0; tt < T_TYPES; ++tt) {
        unsigned long long m = __ballot(t == tt);
        if (m != 0ull) {
            int leader = __ffsll((unsigned long long)m) - 1;
            if (lane == leader) atomicAdd(&misc[tt], (int)__popcll(m));
        }
    }
}

__global__ void offsets_kernel(int* misc) {
    if (threadIdx.x == 0 && blockIdx.x == 0) {
        int s = 0;
        for (int t = 0; t < T_TYPES; ++t) {
            misc[4 + t] = s;                       // type cursor = padded bucket start
            s += ((misc[t] + 63) / 64) * 64;
        }
        int s2 = 0;
        for (int rr = 0; rr < R_TYPES; ++rr) {
            misc[16 + rr] = s2;                    // rel start
            misc[24 + rr] = s2;                    // rel cursor
            s2 += misc[8 + rr];
        }
        misc[23] = s2;                             // == E (end sentinel for r=6)
    }
}

__global__ void perm_scatter(const int* __restrict__ tnt, int* __restrict__ misc,
                             int* __restrict__ perm) {
    int n = blockIdx.x * blockDim.x + threadIdx.x;
    int t = (n < N_NODES) ? tnt[n] : -1;
    int lane = threadIdx.x & 63;
    for (int tt = 0; tt < T_TYPES; ++tt) {
        unsigned long long m = __ballot(t == tt);
        if (m == 0ull) continue;
        int leader = __ffsll((unsigned long long)m) - 1;
        int base = 0;
        if (lane == leader) base = atomicAdd(&misc[4 + tt], (int)__popcll(m));
        base = __shfl(base, leader, 64);
        if (t == tt) {
            int rank = (int)__popcll(m & ((1ull << lane) - 1ull));
            perm[base + rank] = n;
        }
    }
}

__global__ void elist_fill(const int* __restrict__ ei, const int* __restrict__ et,
                           int* __restrict__ misc, int2* __restrict__ elist) {
    int e = blockIdx.x * blockDim.x + threadIdx.x;
    int r = -1, s = 0, d = 0;
    if (e < N_EDGES) {
        r = et[e];
        s = ei[e];
        d = ei[N_EDGES + e];
    }
    int lane = threadIdx.x & 63;
    for (int rr = 0; rr < R_TYPES; ++rr) {
        unsigned long long m = __ballot(r == rr);
        if (m == 0ull) continue;
        int leader = __ffsll((unsigned long long)m) - 1;
        int base = 0;
        if (lane == leader) base = atomicAdd(&misc[24 + rr], (int)__popcll(m));
        base = __shfl(base, leader, 64);
        if (r == rr) {
            int rank = (int)__popcll(m & ((1ull << lane) - 1ull));
            elist[base + rank] = make_int2(s, d);
        }
    }
}

// ---------------- per-relation transform GEMM: xw[n,o] = sum_k x[n,k] * w[o,k]
// BM=128, BN=128, BK=32, 256 threads, 8x8 micro-tile (fp32 vector ALU)
#define ASTR 33
#define BSTR 132
__launch_bounds__(256, 2)
__global__ void xw_gemm(const float* __restrict__ x, const float* __restrict__ w,
                        float* __restrict__ xw) {
    __shared__ float As[128 * ASTR];   // [m][k]
    __shared__ float Bs[32 * BSTR];    // [k][o]
    int tid = threadIdx.x;
    int tx = tid & 15;          // o = tx*4+j and 64+tx*4+j
    int ty = tid >> 4;          // m = ty*8+i
    int n0 = blockIdx.x * 128;
    float acc[8][8];
    #pragma unroll
    for (int i = 0; i < 8; ++i)
        #pragma unroll
        for (int j = 0; j < 8; ++j) acc[i][j] = 0.0f;

    for (int kb = 0; kb < 4; ++kb) {
        #pragma unroll
        for (int p = 0; p < 4; ++p) {         // A tile 128x32
            int idx = p * 256 + tid;
            int row = idx >> 3;
            int cc  = (idx & 7) * 4;
            int node = n0 + row;
            float4 v = make_float4(0.f, 0.f, 0.f, 0.f);
            if (node < N_NODES)
                v = *(const float4*)(x + (size_t)node * C_DIM + kb * 32 + cc);
            As[row * ASTR + cc + 0] = v.x;
            As[row * ASTR + cc + 1] = v.y;
            As[row * ASTR + cc + 2] = v.z;
            As[row * ASTR + cc + 3] = v.w;
        }
        #pragma unroll
        for (int p = 0; p < 4; ++p) {         // B tile 32x128 (transposed store)
            int idx = p * 256 + tid;
            int o  = idx >> 3;
            int cc = (idx & 7) * 4;
            float4 v = *(const float4*)(w + (size_t)o * C_DIM + kb * 32 + cc);
            Bs[(cc + 0) * BSTR + o] = v.x;
            Bs[(cc + 1) * BSTR + o] = v.y;
            Bs[(cc + 2) * BSTR + o] = v.z;
            Bs[(cc + 3) * BSTR + o] = v.w;
        }
        __syncthreads();
        #pragma unroll
        for (int k = 0; k < 32; ++k) {
            float a[8];
            #pragma unroll
            for (int i = 0; i < 8; ++i) a[i] = As[(ty * 8 + i) * ASTR + k];
            float4 b0 = *(const float4*)&Bs[k * BSTR + tx * 4];
            float4 b1 = *(const float4*)&Bs[k * BSTR + 64 + tx * 4];
            float b[8] = {b0.x, b0.y, b0.z, b0.w, b1.x, b1.y, b1.z, b1.w};
            #pragma unroll
            for (int i = 0; i < 8; ++i)
                #pragma unroll
                for (int j = 0; j < 8; ++j) acc[i][j] += a[i] * b[j];
        }
        __syncthreads();
    }
    #pragma unroll
    for (int i = 0; i < 8; ++i) {
        int node = n0 + ty * 8 + i;
        if (node >= N_NODES) continue;
        float4 v0 = {acc[i][0], acc[i][1], acc[i][2], acc[i][3]};
        float4 v1 = {acc[i][4], acc[i][5], acc[i][6], acc[i][7]};
        *(float4*)(xw + (size_t)node * C_DIM + tx * 4) = v0;
        *(float4*)(xw + (size_t)node * C_DIM + 64 + tx * 4) = v1;
    }
}

// ---------------- scatter pass for relation r: out[dst] += xw[src] * inv[dst*R+r]
__global__ void scatter_rel(const int2* __restrict__ elist, const int* __restrict__ misc,
                            const float* __restrict__ inv, const float* __restrict__ xw,
                            float* __restrict__ out, int r) {
    int start = misc[16 + r];
    int len   = misc[17 + r] - start;       // misc[23] == E closes r=6
    int npairs = (len + 1) >> 1;
    int c    = threadIdx.x & 127;
    int half = threadIdx.x >> 7;
    for (int blk = blockIdx.x; blk < npairs; blk += gridDim.x) {
        int li = blk * 2 + half;
        if (li >= len) continue;
        int2 sd = elist[start + li];
        float v = xw[(size_t)sd.x * C_DIM + c] * inv[sd.y * R_TYPES + r];
        unsafeAtomicAdd(&out[(size_t)sd.y * C_DIM + c], v);
    }
}

// ---------------- root GEMM over type-bucketed nodes: out[n] += x[n] @ root_w[t].T + root_b[t]
__launch_bounds__(256, 2)
__global__ void root_gemm(const float* __restrict__ x, const float* __restrict__ root_w,
                          const float* __restrict__ root_b, const int* __restrict__ tnt,
                          const int* __restrict__ perm, float* __restrict__ out) {
    __shared__ int   pidx[64];
    __shared__ float As[64 * ASTR];
    __shared__ float Bs[32 * BSTR];
    int tid = threadIdx.x;
    if (tid < 64) pidx[tid] = perm[blockIdx.x * 64 + tid];
    __syncthreads();
    if (pidx[0] < 0) return;                  // whole block is padding (uniform)
    int t = tnt[pidx[0]];                     // uniform per block by construction
    int tx = tid & 15;                        // o = tx*4+j and 64+tx*4+j
    int ty = tid >> 4;                        // node = ty*4+i
    float acc[4][8];
    #pragma unroll
    for (int i = 0; i < 4; ++i)
        #pragma unroll
        for (int j = 0; j < 8; ++j) acc[i][j] = 0.0f;

    for (int kb = 0; kb < 4; ++kb) {
        #pragma unroll
        for (int p = 0; p < 2; ++p) {         // A tile 64x32 (gather via perm)
            int idx = p * 256 + tid;
            int row = idx >> 3;
            int cc  = (idx & 7) * 4;
            int node = pidx[row];
            float4 v = make_float4(0.f, 0.f, 0.f, 0.f);
            if (node >= 0)
                v = *(const float4*)(x + (size_t)node * C_DIM + kb * 32 + cc);
            As[row * ASTR + cc + 0] = v.x;
            As[row * ASTR + cc + 1] = v.y;
            As[row * ASTR + cc + 2] = v.z;
            As[row * ASTR + cc + 3] = v.w;
        }
        #pragma unroll
        for (int p = 0; p < 4; ++p) {         // B tile 32x128 from root_w[t]
            int idx = p * 256 + tid;
            int o  = idx >> 3;
            int cc = (idx & 7) * 4;
            float4 v = *(const float4*)(root_w + ((size_t)t * 128 + o) * 128 + kb * 32 + cc);
            Bs[(cc + 0) * BSTR + o] = v.x;
            Bs[(cc + 1) * BSTR + o] = v.y;
            Bs[(cc + 2) * BSTR + o] = v.z;
            Bs[(cc + 3) * BSTR + o] = v.w;
        }
        __syncthreads();
        #pragma unroll
        for (int k = 0; k < 32; ++k) {
            float a[4];
            #pragma unroll
            for (int i = 0; i < 4; ++i) a[i] = As[(ty * 4 + i) * ASTR + k];
            float4 b0 = *(const float4*)&Bs[k * BSTR + tx * 4];
            float4 b1 = *(const float4*)&Bs[k * BSTR + 64 + tx * 4];
            float b[8] = {b0.x, b0.y, b0.z, b0.w, b1.x, b1.y, b1.z, b1.w};
            #pragma unroll
            for (int i = 0; i < 4; ++i)
                #pragma unroll
                for (int j = 0; j < 8; ++j) acc[i][j] += a[i] * b[j];
        }
        __syncthreads();
    }
    float4 bias0 = *(const float4*)(root_b + (size_t)t * 128 + tx * 4);
    float4 bias1 = *(const float4*)(root_b + (size_t)t * 128 + 64 + tx * 4);
    #pragma unroll
    for (int i = 0; i < 4; ++i) {
        int node = pidx[ty * 4 + i];
        if (node < 0) continue;
        float* po = out + (size_t)node * C_DIM;
        float4 v0 = *(float4*)(po + tx * 4);
        float4 v1 = *(float4*)(po + 64 + tx * 4);
        v0.x += acc[i][0] + bias0.x;  v0.y += acc[i][1] + bias0.y;
        v0.z += acc[i][2] + bias0.z;  v0.w += acc[i][3] + bias0.w;
        v1.x += acc[i][4] + bias1.x;  v1.y += acc[i][5] + bias1.y;
        v1.z += acc[i][6] + bias1.z;  v1.w += acc[i][7] + bias1.w;
        *(float4*)(po + tx * 4) = v0;
        *(float4*)(po + 64 + tx * 4) = v1;
    }
}

extern "C" void kernel_launch(void* const* d_in, const int* in_sizes, int n_in,
                              void* d_out, int out_size, void* d_ws, size_t ws_size,
                              hipStream_t stream) {
    const float* x      = (const float*)d_in[0];
    const int*   ei     = (const int*)d_in[1];   // [2,E]: src = ei[e], dst = ei[E+e]
    const int*   et     = (const int*)d_in[2];
    const int*   tnt    = (const int*)d_in[3];
    const float* rel_w  = (const float*)d_in[4]; // [R,128,128]
    const float* root_w = (const float*)d_in[5]; // [T,128,128]
    const float* root_b = (const float*)d_in[6]; // [T,128]
    float* out = (float*)d_out;

    char* ws = (char*)d_ws;
    int*   cnti  = (int*)(ws + OFF_CNTI);
    float* inv   = (float*)(ws + OFF_INV);
    int*   misc  = (int*)(ws + OFF_MISC);
    int*   perm  = (int*)(ws + OFF_PERM);
    int2*  elist = (int2*)(ws + OFF_ELIST);
    float* xw    = (float*)(ws + OFF_XW);

    // init: zero cnt/misc, -1-fill perm, zero out (atomics accumulate into it)
    hipMemsetAsync(ws + OFF_CNTI, 0, SEGS * sizeof(int), stream);
    hipMemsetAsync(ws + OFF_MISC, 0, 32 * sizeof(int), stream);
    hipMemsetAsync(ws + OFF_PERM, 0xFF, (size_t)PERM_CAP * sizeof(int), stream);
    hipMemsetAsync(d_out, 0, (size_t)out_size * sizeof(float), stream);

    count_edges <<<N_EDGES / 256, 256, 0, stream>>>(ei, et, cnti, misc);
    type_count  <<<(N_NODES + 255) / 256, 256, 0, stream>>>(tnt, misc);
    inv_kernel  <<<(SEGS + 255) / 256, 256, 0, stream>>>(cnti, inv);
    offsets_kernel<<<1, 64, 0, stream>>>(misc);
    perm_scatter<<<(N_NODES + 255) / 256, 256, 0, stream>>>(tnt, misc, perm);
    elist_fill  <<<N_EDGES / 256, 256, 0, stream>>>(ei, et, misc, elist);

    for (int r = 0; r < R_TYPES; ++r) {
        xw_gemm    <<<(N_NODES + 127) / 128, 256, 0, stream>>>(x, rel_w + (size_t)r * C_DIM * C_DIM, xw);
        scatter_rel<<<2048, 256, 0, stream>>>(elist, misc, inv, xw, out, r);
    }
    root_gemm<<<N_PERM_BLOCKS, 256, 0, stream>>>(x, root_w, root_b, tnt, perm, out);
}

// Round 3
// 1456.876 us; speedup vs baseline: 3.7681x; 3.7681x over previous
//
#include <hip/hip_runtime.h>

#define N_NODES 100000
#define N_EDGES 1600000
#define C_DIM   128
#define R_TYPES 7
#define T_TYPES 4
#define SEGS    (N_NODES * R_TYPES)          // 700000 (dst,rel) segments
#define NB_E    (N_EDGES / 256)              // 6250 edge blocks (exact)
#define NB_N    ((N_NODES + 255) / 256)      // 391 node blocks

// ---- workspace layout (bytes) — total ~70.2 MB ----
#define OFF_CNTI   0ull                       // int  cnt[SEGS]            2.8 MB
#define OFF_INV    2800000ull                 // f32  inv[SEGS]            2.8 MB
#define OFF_MISC   5600000ull                 // int  misc[32]
// misc: [0..3]=type counts, [4..7]=type padded starts, [8..14]=rel counts,
//       [16..23]=rel starts (+[23]=E)
#define OFF_PERM   5600256ull                 // int  perm[PERM_CAP]       0.4 MB
#define PERM_CAP   100288                     // 64 * 1567 (N + per-type pad)
#define N_PERM_BLOCKS 1567
#define OFF_ELIST  6001408ull                 // int2 elist[E] (src,dst)  12.8 MB
#define OFF_BLKE   18801408ull                // int  blk_e[NB_E*8]       200 KB
#define OFF_BLKN   19001408ull                // int  blk_n[NB_N*8]       12.5 KB
#define OFF_XW     19013920ull                // f32  xw[N*128]           51.2 MB
// total = 70,213,920 bytes

// ---------------- phase 1: per-block histograms (LDS, contention-free) -------
__global__ void edge_hist(const int* __restrict__ ei, const int* __restrict__ et,
                          int* __restrict__ cnti, int* __restrict__ blk_e) {
    __shared__ int h[8];
    int tid = threadIdx.x;
    if (tid < 8) h[tid] = 0;
    __syncthreads();
    int e = blockIdx.x * 256 + tid;            // E % 256 == 0, no guard
    int r = et[e];
    int d = ei[N_EDGES + e];
    atomicAdd(&cnti[d * R_TYPES + r], 1);      // 700k distinct addrs: low contention
    atomicAdd(&h[r], 1);                       // LDS: cheap
    __syncthreads();
    if (tid < R_TYPES) blk_e[blockIdx.x * 8 + tid] = h[tid];
}

__global__ void node_hist(const int* __restrict__ tnt, int* __restrict__ blk_n) {
    __shared__ int h[8];
    int tid = threadIdx.x;
    if (tid < 8) h[tid] = 0;
    __syncthreads();
    int n = blockIdx.x * 256 + tid;
    if (n < N_NODES) atomicAdd(&h[tnt[n]], 1);
    __syncthreads();
    if (tid < T_TYPES) blk_n[blockIdx.x * 8 + tid] = h[tid];
}

// ---------------- phase 2: per-type exclusive scan over block partials -------
// one block per type; blk[b*8+type] <- exclusive prefix; total[type] <- sum
__global__ void scan_blocks(int* __restrict__ blk, int nb, int* __restrict__ total) {
    __shared__ int sbuf[256];
    int r = blockIdx.x;
    int tid = threadIdx.x;
    int running = 0;
    for (int c0 = 0; c0 < nb; c0 += 256) {
        int b = c0 + tid;
        int v = (b < nb) ? blk[b * 8 + r] : 0;
        sbuf[tid] = v;
        __syncthreads();
        #pragma unroll
        for (int off = 1; off < 256; off <<= 1) {
            int t = (tid >= off) ? sbuf[tid - off] : 0;
            __syncthreads();
            sbuf[tid] += t;
            __syncthreads();
        }
        int incl = sbuf[tid];
        int chunk_total = sbuf[255];
        __syncthreads();
        if (b < nb) blk[b * 8 + r] = running + incl - v;
        running += chunk_total;
    }
    if (tid == 0) total[r] = running;
}

__global__ void offsets_kernel(int* misc) {
    if (threadIdx.x == 0 && blockIdx.x == 0) {
        int s = 0;
        for (int t = 0; t < T_TYPES; ++t) {
            misc[4 + t] = s;                       // padded bucket start
            s += ((misc[t] + 63) / 64) * 64;
        }
        int s2 = 0;
        for (int rr = 0; rr < R_TYPES; ++rr) {
            misc[16 + rr] = s2;                    // rel start
            s2 += misc[8 + rr];
        }
        misc[23] = s2;                             // == E (end sentinel for r=6)
    }
}

__global__ void inv_kernel(const int* __restrict__ cnti, float* __restrict__ inv) {
    int i = blockIdx.x * blockDim.x + threadIdx.x;
    if (i < SEGS) inv[i] = 1.0f / (float)max(cnti[i], 1);
}

// ---------------- phase 3: replay scatter (positions from scan, LDS ranks) ---
__global__ void edge_scatter(const int* __restrict__ ei, const int* __restrict__ et,
                             const int* __restrict__ misc, const int* __restrict__ blk_e,
                             int2* __restrict__ elist) {
    __shared__ int h[8];
    int tid = threadIdx.x;
    if (tid < 8) h[tid] = 0;
    __syncthreads();
    int e = blockIdx.x * 256 + tid;
    int r = et[e];
    int s = ei[e];
    int d = ei[N_EDGES + e];
    int rank = atomicAdd(&h[r], 1);
    int pos = misc[16 + r] + blk_e[blockIdx.x * 8 + r] + rank;
    elist[pos] = make_int2(s, d);
}

__global__ void node_scatter(const int* __restrict__ tnt, const int* __restrict__ misc,
                             const int* __restrict__ blk_n, int* __restrict__ perm) {
    __shared__ int h[8];
    int tid = threadIdx.x;
    if (tid < 8) h[tid] = 0;
    __syncthreads();
    int n = blockIdx.x * 256 + tid;
    if (n < N_NODES) {
        int t = tnt[n];
        int rank = atomicAdd(&h[t], 1);
        int pos = misc[4 + t] + blk_n[blockIdx.x * 8 + t] + rank;
        perm[pos] = n;
    }
}

// ---------------- per-relation transform GEMM: xw[n,o] = sum_k x[n,k] * w[o,k]
// BM=128, BN=128, BK=32, 256 threads, 8x8 micro-tile (fp32 vector ALU)
#define ASTR 33
#define BSTR 132
__launch_bounds__(256, 2)
__global__ void xw_gemm(const float* __restrict__ x, const float* __restrict__ w,
                        float* __restrict__ xw) {
    __shared__ float As[128 * ASTR];   // [m][k]
    __shared__ float Bs[32 * BSTR];    // [k][o]
    int tid = threadIdx.x;
    int tx = tid & 15;          // o = tx*4+j and 64+tx*4+j
    int ty = tid >> 4;          // m = ty*8+i
    int n0 = blockIdx.x * 128;
    float acc[8][8];
    #pragma unroll
    for (int i = 0; i < 8; ++i)
        #pragma unroll
        for (int j = 0; j < 8; ++j) acc[i][j] = 0.0f;

    for (int kb = 0; kb < 4; ++kb) {
        #pragma unroll
        for (int p = 0; p < 4; ++p) {         // A tile 128x32
            int idx = p * 256 + tid;
            int row = idx >> 3;
            int cc  = (idx & 7) * 4;
            int node = n0 + row;
            float4 v = make_float4(0.f, 0.f, 0.f, 0.f);
            if (node < N_NODES)
                v = *(const float4*)(x + (size_t)node * C_DIM + kb * 32 + cc);
            As[row * ASTR + cc + 0] = v.x;
            As[row * ASTR + cc + 1] = v.y;
            As[row * ASTR + cc + 2] = v.z;
            As[row * ASTR + cc + 3] = v.w;
        }
        #pragma unroll
        for (int p = 0; p < 4; ++p) {         // B tile 32x128 (transposed store)
            int idx = p * 256 + tid;
            int o  = idx >> 3;
            int cc = (idx & 7) * 4;
            float4 v = *(const float4*)(w + (size_t)o * C_DIM + kb * 32 + cc);
            Bs[(cc + 0) * BSTR + o] = v.x;
            Bs[(cc + 1) * BSTR + o] = v.y;
            Bs[(cc + 2) * BSTR + o] = v.z;
            Bs[(cc + 3) * BSTR + o] = v.w;
        }
        __syncthreads();
        #pragma unroll
        for (int k = 0; k < 32; ++k) {
            float a[8];
            #pragma unroll
            for (int i = 0; i < 8; ++i) a[i] = As[(ty * 8 + i) * ASTR + k];
            float4 b0 = *(const float4*)&Bs[k * BSTR + tx * 4];
            float4 b1 = *(const float4*)&Bs[k * BSTR + 64 + tx * 4];
            float b[8] = {b0.x, b0.y, b0.z, b0.w, b1.x, b1.y, b1.z, b1.w};
            #pragma unroll
            for (int i = 0; i < 8; ++i)
                #pragma unroll
                for (int j = 0; j < 8; ++j) acc[i][j] += a[i] * b[j];
        }
        __syncthreads();
    }
    #pragma unroll
    for (int i = 0; i < 8; ++i) {
        int node = n0 + ty * 8 + i;
        if (node >= N_NODES) continue;
        float4 v0 = {acc[i][0], acc[i][1], acc[i][2], acc[i][3]};
        float4 v1 = {acc[i][4], acc[i][5], acc[i][6], acc[i][7]};
        *(float4*)(xw + (size_t)node * C_DIM + tx * 4) = v0;
        *(float4*)(xw + (size_t)node * C_DIM + 64 + tx * 4) = v1;
    }
}

// ---------------- scatter pass for relation r: out[dst] += xw[src] * inv[dst*R+r]
__global__ void scatter_rel(const int2* __restrict__ elist, const int* __restrict__ misc,
                            const float* __restrict__ inv, const float* __restrict__ xw,
                            float* __restrict__ out, int r) {
    int start = misc[16 + r];
    int len   = misc[17 + r] - start;       // misc[23] == E closes r=6
    int npairs = (len + 1) >> 1;
    int c    = threadIdx.x & 127;
    int half = threadIdx.x >> 7;
    for (int blk = blockIdx.x; blk < npairs; blk += gridDim.x) {
        int li = blk * 2 + half;
        if (li >= len) continue;
        int2 sd = elist[start + li];
        float v = xw[(size_t)sd.x * C_DIM + c] * inv[sd.y * R_TYPES + r];
        unsafeAtomicAdd(&out[(size_t)sd.y * C_DIM + c], v);
    }
}

// ---------------- root GEMM over type-bucketed nodes: out[n] += x[n] @ root_w[t].T + root_b[t]
__launch_bounds__(256, 2)
__global__ void root_gemm(const float* __restrict__ x, const float* __restrict__ root_w,
                          const float* __restrict__ root_b, const int* __restrict__ tnt,
                          const int* __restrict__ perm, float* __restrict__ out) {
    __shared__ int   pidx[64];
    __shared__ float As[64 * ASTR];
    __shared__ float Bs[32 * BSTR];
    int tid = threadIdx.x;
    if (tid < 64) pidx[tid] = perm[blockIdx.x * 64 + tid];
    __syncthreads();
    if (pidx[0] < 0) return;                  // whole block is padding (uniform)
    int t = tnt[pidx[0]];                     // uniform per block by construction
    int tx = tid & 15;                        // o = tx*4+j and 64+tx*4+j
    int ty = tid >> 4;                        // node = ty*4+i
    float acc[4][8];
    #pragma unroll
    for (int i = 0; i < 4; ++i)
        #pragma unroll
        for (int j = 0; j < 8; ++j) acc[i][j] = 0.0f;

    for (int kb = 0; kb < 4; ++kb) {
        #pragma unroll
        for (int p = 0; p < 2; ++p) {         // A tile 64x32 (gather via perm)
            int idx = p * 256 + tid;
            int row = idx >> 3;
            int cc  = (idx & 7) * 4;
            int node = pidx[row];
            float4 v = make_float4(0.f, 0.f, 0.f, 0.f);
            if (node >= 0)
                v = *(const float4*)(x + (size_t)node * C_DIM + kb * 32 + cc);
            As[row * ASTR + cc + 0] = v.x;
            As[row * ASTR + cc + 1] = v.y;
            As[row * ASTR + cc + 2] = v.z;
            As[row * ASTR + cc + 3] = v.w;
        }
        #pragma unroll
        for (int p = 0; p < 4; ++p) {         // B tile 32x128 from root_w[t]
            int idx = p * 256 + tid;
            int o  = idx >> 3;
            int cc = (idx & 7) * 4;
            float4 v = *(const float4*)(root_w + ((size_t)t * 128 + o) * 128 + kb * 32 + cc);
            Bs[(cc + 0) * BSTR + o] = v.x;
            Bs[(cc + 1) * BSTR + o] = v.y;
            Bs[(cc + 2) * BSTR + o] = v.z;
            Bs[(cc + 3) * BSTR + o] = v.w;
        }
        __syncthreads();
        #pragma unroll
        for (int k = 0; k < 32; ++k) {
            float a[4];
            #pragma unroll
            for (int i = 0; i < 4; ++i) a[i] = As[(ty * 4 + i) * ASTR + k];
            float4 b0 = *(const float4*)&Bs[k * BSTR + tx * 4];
            float4 b1 = *(const float4*)&Bs[k * BSTR + 64 + tx * 4];
            float b[8] = {b0.x, b0.y, b0.z, b0.w, b1.x, b1.y, b1.z, b1.w};
            #pragma unroll
            for (int i = 0; i < 4; ++i)
                #pragma unroll
                for (int j = 0; j < 8; ++j) acc[i][j] += a[i] * b[j];
        }
        __syncthreads();
    }
    float4 bias0 = *(const float4*)(root_b + (size_t)t * 128 + tx * 4);
    float4 bias1 = *(const float4*)(root_b + (size_t)t * 128 + 64 + tx * 4);
    #pragma unroll
    for (int i = 0; i < 4; ++i) {
        int node = pidx[ty * 4 + i];
        if (node < 0) continue;
        float* po = out + (size_t)node * C_DIM;
        float4 v0 = *(float4*)(po + tx * 4);
        float4 v1 = *(float4*)(po + 64 + tx * 4);
        v0.x += acc[i][0] + bias0.x;  v0.y += acc[i][1] + bias0.y;
        v0.z += acc[i][2] + bias0.z;  v0.w += acc[i][3] + bias0.w;
        v1.x += acc[i][4] + bias1.x;  v1.y += acc[i][5] + bias1.y;
        v1.z += acc[i][6] + bias1.z;  v1.w += acc[i][7] + bias1.w;
        *(float4*)(po + tx * 4) = v0;
        *(float4*)(po + 64 + tx * 4) = v1;
    }
}

extern "C" void kernel_launch(void* const* d_in, const int* in_sizes, int n_in,
                              void* d_out, int out_size, void* d_ws, size_t ws_size,
                              hipStream_t stream) {
    const float* x      = (const float*)d_in[0];
    const int*   ei     = (const int*)d_in[1];   // [2,E]: src = ei[e], dst = ei[E+e]
    const int*   et     = (const int*)d_in[2];
    const int*   tnt    = (const int*)d_in[3];
    const float* rel_w  = (const float*)d_in[4]; // [R,128,128]
    const float* root_w = (const float*)d_in[5]; // [T,128,128]
    const float* root_b = (const float*)d_in[6]; // [T,128]
    float* out = (float*)d_out;

    char* ws = (char*)d_ws;
    int*   cnti  = (int*)(ws + OFF_CNTI);
    float* inv   = (float*)(ws + OFF_INV);
    int*   misc  = (int*)(ws + OFF_MISC);
    int*   perm  = (int*)(ws + OFF_PERM);
    int2*  elist = (int2*)(ws + OFF_ELIST);
    int*   blk_e = (int*)(ws + OFF_BLKE);
    int*   blk_n = (int*)(ws + OFF_BLKN);
    float* xw    = (float*)(ws + OFF_XW);

    hipMemsetAsync(ws + OFF_CNTI, 0, SEGS * sizeof(int), stream);
    hipMemsetAsync(ws + OFF_MISC, 0, 32 * sizeof(int), stream);
    hipMemsetAsync(ws + OFF_PERM, 0xFF, (size_t)PERM_CAP * sizeof(int), stream);
    hipMemsetAsync(d_out, 0, (size_t)out_size * sizeof(float), stream);

    edge_hist   <<<NB_E, 256, 0, stream>>>(ei, et, cnti, blk_e);
    node_hist   <<<NB_N, 256, 0, stream>>>(tnt, blk_n);
    inv_kernel  <<<(SEGS + 255) / 256, 256, 0, stream>>>(cnti, inv);
    scan_blocks <<<R_TYPES, 256, 0, stream>>>(blk_e, NB_E, misc + 8);
    scan_blocks <<<T_TYPES, 256, 0, stream>>>(blk_n, NB_N, misc + 0);
    offsets_kernel<<<1, 64, 0, stream>>>(misc);
    edge_scatter<<<NB_E, 256, 0, stream>>>(ei, et, misc, blk_e, elist);
    node_scatter<<<NB_N, 256, 0, stream>>>(tnt, misc, blk_n, perm);

    for (int r = 0; r < R_TYPES; ++r) {
        xw_gemm    <<<(N_NODES + 127) / 128, 256, 0, stream>>>(x, rel_w + (size_t)r * C_DIM * C_DIM, xw);
        scatter_rel<<<2048, 256, 0, stream>>>(elist, misc, inv, xw, out, r);
    }
    root_gemm<<<N_PERM_BLOCKS, 256, 0, stream>>>(x, root_w, root_b, tnt, perm, out);
}

// Round 4
// 798.553 us; speedup vs baseline: 6.8746x; 1.8244x over previous
//
#include <hip/hip_runtime.h>

#define N_NODES 100000
#define N_EDGES 1600000
#define C_DIM   128
#define R_TYPES 7
#define T_TYPES 4
#define SEGS    (N_NODES * R_TYPES)          // 700000 (dst,rel) segments
#define NB_E    (N_EDGES / 256)              // 6250 (E % 256 == 0)
#define NB_N    ((N_NODES + 255) / 256)      // 391
#define NB_S    ((SEGS + 255) / 256)         // 2735 segment-scan blocks
#define XP_ROWS 100096                       // N padded to 128-row tiles (782 tiles)

// ---- workspace layout (bytes) — total ~66.7 MB ----
#define OFF_CNTI   0ull                       // int  cnti[SEGS]           2.80 MB
#define OFF_SEGO   2800000ull                 // int  seg_off[SEGS+1]      2.80 MB
#define OFF_CURS   5600004ull                 // int  cursor[SEGS]         2.80 MB
#define OFF_MISC   8400004ull                 // int  misc[32]  [0..3]=type cnt, [4..7]=type start
#define OFF_PERM   8400132ull                 // int  perm[PERM_CAP]       0.40 MB
#define PERM_CAP   100288
#define N_PERM_BLOCKS 1567
#define OFF_BLKN   8801284ull                 // int  blk_n[NB_N*8]
#define OFF_BSUM   8813796ull                 // int  bsum[NB_S]
#define OFF_ESRC   8824756ull                 // int  esrc[E]              6.40 MB
#define OFF_XP     15224768ull                // bf16 xp[XP_ROWS*128] frag-ordered  25.6 MB
#define OFF_WF     40849344ull                // bf16 wf[7*128*128] frag-ordered    0.23 MB
#define OFF_XWB    41078720ull                // bf16 xwb[XP_ROWS*128]              25.6 MB
// end = 66,703,296

typedef __attribute__((ext_vector_type(8))) short short8;
typedef __attribute__((ext_vector_type(4))) float f32x4;

__device__ inline unsigned short f2bf(float f) {
    unsigned int u = __float_as_uint(f);
    u += 0x7fffu + ((u >> 16) & 1u);          // RNE
    return (unsigned short)(u >> 16);
}
__device__ inline float bf2f(unsigned int h) { return __uint_as_float(h << 16); }

// ---------------- segment counting + CSR ----------------
__global__ void edge_hist(const int* __restrict__ ei, const int* __restrict__ et,
                          int* __restrict__ cnti) {
    int e = blockIdx.x * 256 + threadIdx.x;
    atomicAdd(&cnti[ei[N_EDGES + e] * R_TYPES + et[e]], 1);   // 700k addrs: low contention
}

__global__ void seg_scan1(const int* __restrict__ cnti, int* __restrict__ seg_off,
                          int* __restrict__ bsum) {
    __shared__ int sbuf[256];
    int tid = threadIdx.x;
    int i = blockIdx.x * 256 + tid;
    int v = (i < SEGS) ? cnti[i] : 0;
    sbuf[tid] = v;
    __syncthreads();
    #pragma unroll
    for (int off = 1; off < 256; off <<= 1) {
        int t = (tid >= off) ? sbuf[tid - off] : 0;
        __syncthreads();
        sbuf[tid] += t;
        __syncthreads();
    }
    int incl = sbuf[tid];
    if (i < SEGS) seg_off[i] = incl - v;      // exclusive within chunk
    if (tid == 255) bsum[blockIdx.x] = incl;  // chunk total
}

__global__ void seg_scan2(int* __restrict__ bsum, int nb) {   // 1 block
    __shared__ int sbuf[256];
    int tid = threadIdx.x;
    int running = 0;
    for (int c0 = 0; c0 < nb; c0 += 256) {
        int b = c0 + tid;
        int v = (b < nb) ? bsum[b] : 0;
        sbuf[tid] = v;
        __syncthreads();
        #pragma unroll
        for (int off = 1; off < 256; off <<= 1) {
            int t = (tid >= off) ? sbuf[tid - off] : 0;
            __syncthreads();
            sbuf[tid] += t;
            __syncthreads();
        }
        int incl = sbuf[tid];
        int tot = sbuf[255];
        __syncthreads();
        if (b < nb) bsum[b] = running + incl - v;
        running += tot;
    }
}

__global__ void seg_scan3(int* __restrict__ seg_off, int* __restrict__ cursor,
                          const int* __restrict__ bsum) {
    int i = blockIdx.x * 256 + threadIdx.x;
    if (i < SEGS) {
        int val = seg_off[i] + bsum[blockIdx.x];
        seg_off[i] = val;
        cursor[i] = val;
    }
    if (i == 0) seg_off[SEGS] = N_EDGES;
}

__global__ void place_edges(const int* __restrict__ ei, const int* __restrict__ et,
                            int* __restrict__ cursor, int* __restrict__ esrc) {
    int e = blockIdx.x * 256 + threadIdx.x;
    int s = ei[N_EDGES + e] * R_TYPES + et[e];
    int pos = atomicAdd(&cursor[s], 1);
    esrc[pos] = ei[e];
}

// ---------------- node-type bucketing (for root_gemm) ----------------
__global__ void node_hist(const int* __restrict__ tnt, int* __restrict__ blk_n) {
    __shared__ int h[8];
    int tid = threadIdx.x;
    if (tid < 8) h[tid] = 0;
    __syncthreads();
    int n = blockIdx.x * 256 + tid;
    if (n < N_NODES) atomicAdd(&h[tnt[n]], 1);
    __syncthreads();
    if (tid < T_TYPES) blk_n[blockIdx.x * 8 + tid] = h[tid];
}

__global__ void scan_blocks(int* __restrict__ blk, int nb, int* __restrict__ total) {
    __shared__ int sbuf[256];
    int r = blockIdx.x;
    int tid = threadIdx.x;
    int running = 0;
    for (int c0 = 0; c0 < nb; c0 += 256) {
        int b = c0 + tid;
        int v = (b < nb) ? blk[b * 8 + r] : 0;
        sbuf[tid] = v;
        __syncthreads();
        #pragma unroll
        for (int off = 1; off < 256; off <<= 1) {
            int t = (tid >= off) ? sbuf[tid - off] : 0;
            __syncthreads();
            sbuf[tid] += t;
            __syncthreads();
        }
        int incl = sbuf[tid];
        int chunk_total = sbuf[255];
        __syncthreads();
        if (b < nb) blk[b * 8 + r] = running + incl - v;
        running += chunk_total;
    }
    if (tid == 0) total[r] = running;
}

__global__ void offsets_kernel(int* misc) {
    if (threadIdx.x == 0 && blockIdx.x == 0) {
        int s = 0;
        for (int t = 0; t < T_TYPES; ++t) {
            misc[4 + t] = s;
            s += ((misc[t] + 63) / 64) * 64;
        }
    }
}

__global__ void node_scatter(const int* __restrict__ tnt, const int* __restrict__ misc,
                             const int* __restrict__ blk_n, int* __restrict__ perm) {
    __shared__ int h[8];
    int tid = threadIdx.x;
    if (tid < 8) h[tid] = 0;
    __syncthreads();
    int n = blockIdx.x * 256 + tid;
    if (n < N_NODES) {
        int t = tnt[n];
        int rank = atomicAdd(&h[t], 1);
        perm[misc[4 + t] + blk_n[blockIdx.x * 8 + t] + rank] = n;
    }
}

// ---------------- bf16 fragment-layout conversions ----------------
// frag index for (n,k): (n>>4)*2048 + (k>>5)*512 + ((k>>3)&3)*128 + (n&15)*8 + (k&7)
// => a wave's 16x32 fragment tile is lane-linear 16B loads.
__global__ void cvt_x_frag(const float* __restrict__ x, unsigned short* __restrict__ xp) {
    int id = blockIdx.x * 256 + threadIdx.x;       // XP_ROWS*16 exact
    int n = id >> 4, ko = id & 15;
    short8 o;
    if (n < N_NODES) {
        const float4* px = (const float4*)(x + (size_t)n * C_DIM + ko * 8);
        float4 a = px[0], b = px[1];
        o[0] = (short)f2bf(a.x); o[1] = (short)f2bf(a.y);
        o[2] = (short)f2bf(a.z); o[3] = (short)f2bf(a.w);
        o[4] = (short)f2bf(b.x); o[5] = (short)f2bf(b.y);
        o[6] = (short)f2bf(b.z); o[7] = (short)f2bf(b.w);
    } else {
        o = (short8)0;
    }
    size_t off = (size_t)(n >> 4) * 2048 + (ko >> 2) * 512 + (ko & 3) * 128 + (n & 15) * 8;
    *(short8*)(xp + off) = o;
}

__global__ void cvt_w_frag(const float* __restrict__ rel_w, unsigned short* __restrict__ wf) {
    int id = blockIdx.x * 256 + threadIdx.x;       // 7*128*16 = 14336 exact
    if (id >= R_TYPES * 128 * 16) return;
    int r = id >> 11, rest = id & 2047;
    int o = rest >> 4, ko = rest & 15;
    const float4* pw = (const float4*)(rel_w + (size_t)r * 16384 + o * 128 + ko * 8);
    float4 a = pw[0], b = pw[1];
    short8 v;
    v[0] = (short)f2bf(a.x); v[1] = (short)f2bf(a.y);
    v[2] = (short)f2bf(a.z); v[3] = (short)f2bf(a.w);
    v[4] = (short)f2bf(b.x); v[5] = (short)f2bf(b.y);
    v[6] = (short)f2bf(b.z); v[7] = (short)f2bf(b.w);
    size_t off = (size_t)r * 16384 + (o >> 4) * 2048 + (ko >> 2) * 512 + (ko & 3) * 128 + (o & 15) * 8;
    *(short8*)(wf + off) = v;
}

// ---------------- MFMA bf16 GEMM: xwb[n,o] = sum_k x[n,k]*W[o,k]  (M=100k,N=128,K=128)
// 256 thr = 4 waves; wave owns 32 rows; no LDS (frag-ordered global inputs).
__launch_bounds__(256)
__global__ void xw_gemm_mfma(const unsigned short* __restrict__ xp,
                             const unsigned short* __restrict__ wf,
                             unsigned short* __restrict__ xwb, int r) {
    int wave = threadIdx.x >> 6, lane = threadIdx.x & 63;
    int m0 = blockIdx.x * 128;
    const unsigned short* wr = wf + (size_t)r * 16384;

    short8 a[4][2];
    #pragma unroll
    for (int kb = 0; kb < 4; ++kb)
        #pragma unroll
        for (int rt = 0; rt < 2; ++rt) {
            size_t rtile = (size_t)blockIdx.x * 8 + wave * 2 + rt;
            a[kb][rt] = *(const short8*)(xp + rtile * 2048 + kb * 512 + lane * 8);
        }

    f32x4 acc[2][8];
    #pragma unroll
    for (int rt = 0; rt < 2; ++rt)
        #pragma unroll
        for (int ct = 0; ct < 8; ++ct) acc[rt][ct] = (f32x4)0.0f;

    #pragma unroll
    for (int ct = 0; ct < 8; ++ct) {
        #pragma unroll
        for (int kb = 0; kb < 4; ++kb) {
            short8 b = *(const short8*)(wr + (size_t)ct * 2048 + kb * 512 + lane * 8);
            #pragma unroll
            for (int rt = 0; rt < 2; ++rt)
                acc[rt][ct] = __builtin_amdgcn_mfma_f32_16x16x32_bf16(a[kb][rt], b, acc[rt][ct], 0, 0, 0);
        }
    }
    // C/D layout: col = lane&15, row = (lane>>4)*4 + i   [m89-verified]
    int col = lane & 15, rq = (lane >> 4) * 4;
    #pragma unroll
    for (int rt = 0; rt < 2; ++rt)
        #pragma unroll
        for (int ct = 0; ct < 8; ++ct)
            #pragma unroll
            for (int i = 0; i < 4; ++i) {
                int n = m0 + wave * 32 + rt * 16 + rq + i;
                if (n < N_NODES)
                    xwb[(size_t)n * C_DIM + ct * 16 + col] = f2bf(acc[rt][ct][i]);
            }
}

// ---------------- per-relation gather: out[dst] += mean over segment (dst,r) of xwb[src]
// one wave per dst; lane handles channels (2*lane, 2*lane+1); plain RMW, no atomics.
__global__ void gather_rel(const int* __restrict__ seg_off, const int* __restrict__ esrc,
                           const unsigned short* __restrict__ xwb, float* __restrict__ out,
                           int r) {
    int wave = threadIdx.x >> 6, lane = threadIdx.x & 63;
    int dst = blockIdx.x * 4 + wave;
    if (dst >= N_NODES) return;
    int s = dst * R_TYPES + r;
    int o0 = seg_off[s], o1 = seg_off[s + 1];
    if (o1 <= o0) return;
    float ax = 0.0f, ay = 0.0f;
    for (int e = o0; e < o1; ++e) {
        int src = esrc[e];
        unsigned int pk = *(const unsigned int*)(xwb + (size_t)src * C_DIM + lane * 2);
        ax += bf2f(pk & 0xffffu);
        ay += bf2f(pk >> 16);
    }
    float sc = 1.0f / (float)(o1 - o0);
    float2* po = (float2*)(out + (size_t)dst * C_DIM) + lane;
    float2 v = *po;
    v.x += ax * sc;
    v.y += ay * sc;
    *po = v;
}

// ---------------- root GEMM over type-bucketed nodes (fp32, unchanged) ----------------
#define ASTR 33
#define BSTR 132
__launch_bounds__(256, 2)
__global__ void root_gemm(const float* __restrict__ x, const float* __restrict__ root_w,
                          const float* __restrict__ root_b, const int* __restrict__ tnt,
                          const int* __restrict__ perm, float* __restrict__ out) {
    __shared__ int   pidx[64];
    __shared__ float As[64 * ASTR];
    __shared__ float Bs[32 * BSTR];
    int tid = threadIdx.x;
    if (tid < 64) pidx[tid] = perm[blockIdx.x * 64 + tid];
    __syncthreads();
    if (pidx[0] < 0) return;
    int t = tnt[pidx[0]];
    int tx = tid & 15;
    int ty = tid >> 4;
    float acc[4][8];
    #pragma unroll
    for (int i = 0; i < 4; ++i)
        #pragma unroll
        for (int j = 0; j < 8; ++j) acc[i][j] = 0.0f;

    for (int kb = 0; kb < 4; ++kb) {
        #pragma unroll
        for (int p = 0; p < 2; ++p) {
            int idx = p * 256 + tid;
            int row = idx >> 3;
            int cc  = (idx & 7) * 4;
            int node = pidx[row];
            float4 v = make_float4(0.f, 0.f, 0.f, 0.f);
            if (node >= 0)
                v = *(const float4*)(x + (size_t)node * C_DIM + kb * 32 + cc);
            As[row * ASTR + cc + 0] = v.x;
            As[row * ASTR + cc + 1] = v.y;
            As[row * ASTR + cc + 2] = v.z;
            As[row * ASTR + cc + 3] = v.w;
        }
        #pragma unroll
        for (int p = 0; p < 4; ++p) {
            int idx = p * 256 + tid;
            int o  = idx >> 3;
            int cc = (idx & 7) * 4;
            float4 v = *(const float4*)(root_w + ((size_t)t * 128 + o) * 128 + kb * 32 + cc);
            Bs[(cc + 0) * BSTR + o] = v.x;
            Bs[(cc + 1) * BSTR + o] = v.y;
            Bs[(cc + 2) * BSTR + o] = v.z;
            Bs[(cc + 3) * BSTR + o] = v.w;
        }
        __syncthreads();
        #pragma unroll
        for (int k = 0; k < 32; ++k) {
            float a[4];
            #pragma unroll
            for (int i = 0; i < 4; ++i) a[i] = As[(ty * 4 + i) * ASTR + k];
            float4 b0 = *(const float4*)&Bs[k * BSTR + tx * 4];
            float4 b1 = *(const float4*)&Bs[k * BSTR + 64 + tx * 4];
            float b[8] = {b0.x, b0.y, b0.z, b0.w, b1.x, b1.y, b1.z, b1.w};
            #pragma unroll
            for (int i = 0; i < 4; ++i)
                #pragma unroll
                for (int j = 0; j < 8; ++j) acc[i][j] += a[i] * b[j];
        }
        __syncthreads();
    }
    float4 bias0 = *(const float4*)(root_b + (size_t)t * 128 + tx * 4);
    float4 bias1 = *(const float4*)(root_b + (size_t)t * 128 + 64 + tx * 4);
    #pragma unroll
    for (int i = 0; i < 4; ++i) {
        int node = pidx[ty * 4 + i];
        if (node < 0) continue;
        float* po = out + (size_t)node * C_DIM;
        float4 v0 = *(float4*)(po + tx * 4);
        float4 v1 = *(float4*)(po + 64 + tx * 4);
        v0.x += acc[i][0] + bias0.x;  v0.y += acc[i][1] + bias0.y;
        v0.z += acc[i][2] + bias0.z;  v0.w += acc[i][3] + bias0.w;
        v1.x += acc[i][4] + bias1.x;  v1.y += acc[i][5] + bias1.y;
        v1.z += acc[i][6] + bias1.z;  v1.w += acc[i][7] + bias1.w;
        *(float4*)(po + tx * 4) = v0;
        *(float4*)(po + 64 + tx * 4) = v1;
    }
}

extern "C" void kernel_launch(void* const* d_in, const int* in_sizes, int n_in,
                              void* d_out, int out_size, void* d_ws, size_t ws_size,
                              hipStream_t stream) {
    const float* x      = (const float*)d_in[0];
    const int*   ei     = (const int*)d_in[1];
    const int*   et     = (const int*)d_in[2];
    const int*   tnt    = (const int*)d_in[3];
    const float* rel_w  = (const float*)d_in[4];
    const float* root_w = (const float*)d_in[5];
    const float* root_b = (const float*)d_in[6];
    float* out = (float*)d_out;

    char* ws = (char*)d_ws;
    int*   cnti   = (int*)(ws + OFF_CNTI);
    int*   seg_off= (int*)(ws + OFF_SEGO);
    int*   cursor = (int*)(ws + OFF_CURS);
    int*   misc   = (int*)(ws + OFF_MISC);
    int*   perm   = (int*)(ws + OFF_PERM);
    int*   blk_n  = (int*)(ws + OFF_BLKN);
    int*   bsum   = (int*)(ws + OFF_BSUM);
    int*   esrc   = (int*)(ws + OFF_ESRC);
    unsigned short* xp  = (unsigned short*)(ws + OFF_XP);
    unsigned short* wf  = (unsigned short*)(ws + OFF_WF);
    unsigned short* xwb = (unsigned short*)(ws + OFF_XWB);

    hipMemsetAsync(ws + OFF_CNTI, 0, SEGS * sizeof(int), stream);
    hipMemsetAsync(ws + OFF_MISC, 0, 32 * sizeof(int), stream);
    hipMemsetAsync(ws + OFF_PERM, 0xFF, (size_t)PERM_CAP * sizeof(int), stream);
    hipMemsetAsync(d_out, 0, (size_t)out_size * sizeof(float), stream);

    // CSR sort of edges by (dst, rel)
    edge_hist  <<<NB_E, 256, 0, stream>>>(ei, et, cnti);
    seg_scan1  <<<NB_S, 256, 0, stream>>>(cnti, seg_off, bsum);
    seg_scan2  <<<1, 256, 0, stream>>>(bsum, NB_S);
    seg_scan3  <<<NB_S, 256, 0, stream>>>(seg_off, cursor, bsum);
    place_edges<<<NB_E, 256, 0, stream>>>(ei, et, cursor, esrc);

    // node-type buckets for root linear
    node_hist  <<<NB_N, 256, 0, stream>>>(tnt, blk_n);
    scan_blocks<<<T_TYPES, 256, 0, stream>>>(blk_n, NB_N, misc + 0);
    offsets_kernel<<<1, 64, 0, stream>>>(misc);
    node_scatter<<<NB_N, 256, 0, stream>>>(tnt, misc, blk_n, perm);

    // bf16 fragment-layout conversions
    cvt_x_frag<<<(XP_ROWS * 16) / 256, 256, 0, stream>>>(x, xp);
    cvt_w_frag<<<56, 256, 0, stream>>>(rel_w, wf);

    for (int r = 0; r < R_TYPES; ++r) {
        xw_gemm_mfma<<<XP_ROWS / 128, 256, 0, stream>>>(xp, wf, xwb, r);
        gather_rel  <<<(N_NODES + 3) / 4, 256, 0, stream>>>(seg_off, esrc, xwb, out, r);
    }
    root_gemm<<<N_PERM_BLOCKS, 256, 0, stream>>>(x, root_w, root_b, tnt, perm, out);
}

// Round 5
// 624.177 us; speedup vs baseline: 8.7951x; 1.2794x over previous
//
#include <hip/hip_runtime.h>

#define N_NODES 100000
#define N_EDGES 1600000
#define C_DIM   128
#define R_TYPES 7
#define T_TYPES 4
#define SEGS    (N_NODES * R_TYPES)          // 700000 (dst,rel) segments
#define NB_E    (N_EDGES / 256)              // 6250 (E % 256 == 0)
#define NB_N    ((N_NODES + 255) / 256)      // 391 node blocks (also dst-scan blocks)
#define XP_ROWS 100096                       // N padded to 128-row tiles (782 tiles)

// ---- workspace layout (bytes) ----
#define OFF_CNTI   0ull                       // int  cnti[SEGS]            2.80 MB
#define OFF_INV    2800000ull                 // f32  inv[SEGS]             2.80 MB
#define OFF_DOFF   5600000ull                 // int  dst_off[N+1]          0.40 MB
#define OFF_CURS   6000004ull                 // int  cursor[N]             0.40 MB
#define OFF_MISC   6400004ull                 // int  misc[32]
#define OFF_PERM   6400132ull                 // int  perm[PERM_CAP]        0.40 MB
#define PERM_CAP   100288
#define N_PERM_BLOCKS 1567
#define OFF_BLKN   6801284ull                 // int  blk_n[NB_N*8]
#define OFF_BSUM   6813796ull                 // int  bsum[NB_N]
#define OFF_ESRC   6815360ull                 // int  esrc[E] packed r<<17|src  6.4 MB
#define OFF_XP     13215360ull                // bf16 xp[XP_ROWS*128] frag     25.6 MB
#define OFF_WF     38839936ull                // bf16 wf[7*128*128] frag        0.23 MB
#define OFF_XWB    39069312ull                // bf16 xwb: full = 7 planes, fallback = 1
#define XWB_PLANE  ((size_t)XP_ROWS * 128)    // elements per relation plane
#define FULL_NEED  218441344ull               // OFF_XWB + 7*25,624,576
#define FB_NEED    64693888ull                // OFF_XWB + 1*25,624,576

typedef __attribute__((ext_vector_type(8))) short short8;
typedef __attribute__((ext_vector_type(4))) float f32x4;

__device__ inline unsigned short f2bf(float f) {
    unsigned int u = __float_as_uint(f);
    u += 0x7fffu + ((u >> 16) & 1u);          // RNE
    return (unsigned short)(u >> 16);
}
__device__ inline float bf2f(unsigned int h) { return __uint_as_float(h << 16); }

// ---------------- per-(dst,rel) counts ----------------
__global__ void edge_hist(const int* __restrict__ ei, const int* __restrict__ et,
                          int* __restrict__ cnti) {
    int e = blockIdx.x * 256 + threadIdx.x;
    atomicAdd(&cnti[ei[N_EDGES + e] * R_TYPES + et[e]], 1);   // 700k addrs: low contention
}

__global__ void inv_kernel(const int* __restrict__ cnti, float* __restrict__ inv) {
    int i = blockIdx.x * blockDim.x + threadIdx.x;
    if (i < SEGS) inv[i] = 1.0f / (float)max(cnti[i], 1);
}

// ---------------- dst-CSR: dst_off = exclusive scan of per-dst degree ----------------
__global__ void dst_scan1(const int* __restrict__ cnti, int* __restrict__ dst_off,
                          int* __restrict__ bsum) {
    __shared__ int sbuf[256];
    int tid = threadIdx.x;
    int i = blockIdx.x * 256 + tid;
    int v = 0;
    if (i < N_NODES) {
        #pragma unroll
        for (int r = 0; r < R_TYPES; ++r) v += cnti[i * R_TYPES + r];
    }
    sbuf[tid] = v;
    __syncthreads();
    #pragma unroll
    for (int off = 1; off < 256; off <<= 1) {
        int t = (tid >= off) ? sbuf[tid - off] : 0;
        __syncthreads();
        sbuf[tid] += t;
        __syncthreads();
    }
    int incl = sbuf[tid];
    if (i < N_NODES) dst_off[i] = incl - v;   // exclusive within chunk
    if (tid == 255) bsum[blockIdx.x] = incl;
}

__global__ void seg_scan2(int* __restrict__ bsum, int nb) {   // 1 block
    __shared__ int sbuf[256];
    int tid = threadIdx.x;
    int running = 0;
    for (int c0 = 0; c0 < nb; c0 += 256) {
        int b = c0 + tid;
        int v = (b < nb) ? bsum[b] : 0;
        sbuf[tid] = v;
        __syncthreads();
        #pragma unroll
        for (int off = 1; off < 256; off <<= 1) {
            int t = (tid >= off) ? sbuf[tid - off] : 0;
            __syncthreads();
            sbuf[tid] += t;
            __syncthreads();
        }
        int incl = sbuf[tid];
        int tot = sbuf[255];
        __syncthreads();
        if (b < nb) bsum[b] = running + incl - v;
        running += tot;
    }
}

__global__ void dst_scan3(int* __restrict__ dst_off, int* __restrict__ cursor,
                          const int* __restrict__ bsum) {
    int i = blockIdx.x * 256 + threadIdx.x;
    if (i < N_NODES) {
        int val = dst_off[i] + bsum[blockIdx.x];
        dst_off[i] = val;
        cursor[i] = val;
    }
    if (i == 0) dst_off[N_NODES] = N_EDGES;
}

__global__ void place_edges(const int* __restrict__ ei, const int* __restrict__ et,
                            int* __restrict__ cursor, int* __restrict__ esrc) {
    int e = blockIdx.x * 256 + threadIdx.x;
    int d = ei[N_EDGES + e];
    int pos = atomicAdd(&cursor[d], 1);
    esrc[pos] = (et[e] << 17) | ei[e];        // r in [17:20), src in [0:17)
}

// ---------------- node-type bucketing (for root_gemm) ----------------
__global__ void node_hist(const int* __restrict__ tnt, int* __restrict__ blk_n) {
    __shared__ int h[8];
    int tid = threadIdx.x;
    if (tid < 8) h[tid] = 0;
    __syncthreads();
    int n = blockIdx.x * 256 + tid;
    if (n < N_NODES) atomicAdd(&h[tnt[n]], 1);
    __syncthreads();
    if (tid < T_TYPES) blk_n[blockIdx.x * 8 + tid] = h[tid];
}

__global__ void scan_blocks(int* __restrict__ blk, int nb, int* __restrict__ total) {
    __shared__ int sbuf[256];
    int r = blockIdx.x;
    int tid = threadIdx.x;
    int running = 0;
    for (int c0 = 0; c0 < nb; c0 += 256) {
        int b = c0 + tid;
        int v = (b < nb) ? blk[b * 8 + r] : 0;
        sbuf[tid] = v;
        __syncthreads();
        #pragma unroll
        for (int off = 1; off < 256; off <<= 1) {
            int t = (tid >= off) ? sbuf[tid - off] : 0;
            __syncthreads();
            sbuf[tid] += t;
            __syncthreads();
        }
        int incl = sbuf[tid];
        int chunk_total = sbuf[255];
        __syncthreads();
        if (b < nb) blk[b * 8 + r] = running + incl - v;
        running += chunk_total;
    }
    if (tid == 0) total[r] = running;
}

__global__ void offsets_kernel(int* misc) {
    if (threadIdx.x == 0 && blockIdx.x == 0) {
        int s = 0;
        for (int t = 0; t < T_TYPES; ++t) {
            misc[4 + t] = s;
            s += ((misc[t] + 63) / 64) * 64;
        }
    }
}

__global__ void node_scatter(const int* __restrict__ tnt, const int* __restrict__ misc,
                             const int* __restrict__ blk_n, int* __restrict__ perm) {
    __shared__ int h[8];
    int tid = threadIdx.x;
    if (tid < 8) h[tid] = 0;
    __syncthreads();
    int n = blockIdx.x * 256 + tid;
    if (n < N_NODES) {
        int t = tnt[n];
        int rank = atomicAdd(&h[t], 1);
        perm[misc[4 + t] + blk_n[blockIdx.x * 8 + t] + rank] = n;
    }
}

// ---------------- bf16 fragment-layout conversions ----------------
__global__ void cvt_x_frag(const float* __restrict__ x, unsigned short* __restrict__ xp) {
    int id = blockIdx.x * 256 + threadIdx.x;       // XP_ROWS*16 exact
    int n = id >> 4, ko = id & 15;
    short8 o;
    if (n < N_NODES) {
        const float4* px = (const float4*)(x + (size_t)n * C_DIM + ko * 8);
        float4 a = px[0], b = px[1];
        o[0] = (short)f2bf(a.x); o[1] = (short)f2bf(a.y);
        o[2] = (short)f2bf(a.z); o[3] = (short)f2bf(a.w);
        o[4] = (short)f2bf(b.x); o[5] = (short)f2bf(b.y);
        o[6] = (short)f2bf(b.z); o[7] = (short)f2bf(b.w);
    } else {
        o = (short8)0;
    }
    size_t off = (size_t)(n >> 4) * 2048 + (ko >> 2) * 512 + (ko & 3) * 128 + (n & 15) * 8;
    *(short8*)(xp + off) = o;
}

__global__ void cvt_w_frag(const float* __restrict__ rel_w, unsigned short* __restrict__ wf) {
    int id = blockIdx.x * 256 + threadIdx.x;       // 7*128*16 = 14336 exact
    if (id >= R_TYPES * 128 * 16) return;
    int r = id >> 11, rest = id & 2047;
    int o = rest >> 4, ko = rest & 15;
    const float4* pw = (const float4*)(rel_w + (size_t)r * 16384 + o * 128 + ko * 8);
    float4 a = pw[0], b = pw[1];
    short8 v;
    v[0] = (short)f2bf(a.x); v[1] = (short)f2bf(a.y);
    v[2] = (short)f2bf(a.z); v[3] = (short)f2bf(a.w);
    v[4] = (short)f2bf(b.x); v[5] = (short)f2bf(b.y);
    v[6] = (short)f2bf(b.z); v[7] = (short)f2bf(b.w);
    size_t off = (size_t)r * 16384 + (o >> 4) * 2048 + (ko >> 2) * 512 + (ko & 3) * 128 + (o & 15) * 8;
    *(short8*)(wf + off) = v;
}

// ---------------- MFMA bf16 GEMM: xwb[n,o] = sum_k x[n,k]*W_r[o,k]
__launch_bounds__(256)
__global__ void xw_gemm_mfma(const unsigned short* __restrict__ xp,
                             const unsigned short* __restrict__ wf,
                             unsigned short* __restrict__ xwb, int r) {
    int wave = threadIdx.x >> 6, lane = threadIdx.x & 63;
    int m0 = blockIdx.x * 128;
    const unsigned short* wr = wf + (size_t)r * 16384;

    short8 a[4][2];
    #pragma unroll
    for (int kb = 0; kb < 4; ++kb)
        #pragma unroll
        for (int rt = 0; rt < 2; ++rt) {
            size_t rtile = (size_t)blockIdx.x * 8 + wave * 2 + rt;
            a[kb][rt] = *(const short8*)(xp + rtile * 2048 + kb * 512 + lane * 8);
        }

    f32x4 acc[2][8];
    #pragma unroll
    for (int rt = 0; rt < 2; ++rt)
        #pragma unroll
        for (int ct = 0; ct < 8; ++ct) acc[rt][ct] = (f32x4)0.0f;

    #pragma unroll
    for (int ct = 0; ct < 8; ++ct) {
        #pragma unroll
        for (int kb = 0; kb < 4; ++kb) {
            short8 b = *(const short8*)(wr + (size_t)ct * 2048 + kb * 512 + lane * 8);
            #pragma unroll
            for (int rt = 0; rt < 2; ++rt)
                acc[rt][ct] = __builtin_amdgcn_mfma_f32_16x16x32_bf16(a[kb][rt], b, acc[rt][ct], 0, 0, 0);
        }
    }
    int col = lane & 15, rq = (lane >> 4) * 4;     // C/D: col=lane&15,row=(lane>>4)*4+i
    #pragma unroll
    for (int rt = 0; rt < 2; ++rt)
        #pragma unroll
        for (int ct = 0; ct < 8; ++ct)
            #pragma unroll
            for (int i = 0; i < 4; ++i) {
                int n = m0 + wave * 32 + rt * 16 + rq + i;
                if (n < N_NODES)
                    xwb[(size_t)n * C_DIM + ct * 16 + col] = f2bf(acc[rt][ct][i]);
            }
}

// ---------------- fused gather: out[d] = sum over d's edges of xwb7[r][src]*inv[d*7+r]
// one wave per dst; lane handles channels (2*lane, 2*lane+1); single plain store.
__global__ void gather_fused(const int* __restrict__ dst_off, const int* __restrict__ esrc,
                             const float* __restrict__ inv,
                             const unsigned short* __restrict__ xwb7,
                             float* __restrict__ out) {
    int wave = threadIdx.x >> 6, lane = threadIdx.x & 63;
    int d = blockIdx.x * 4 + wave;
    if (d >= N_NODES) return;
    int o0 = dst_off[d], o1 = dst_off[d + 1];
    float ax = 0.0f, ay = 0.0f;
    int pk_next = (o0 < o1) ? esrc[o0] : 0;
    for (int e = o0; e < o1; ++e) {
        int pk = pk_next;
        if (e + 1 < o1) pk_next = esrc[e + 1];
        int src = pk & 0x1ffff;
        int r   = pk >> 17;
        float sc = inv[d * R_TYPES + r];
        unsigned int row = *(const unsigned int*)(xwb7 + ((size_t)r * XP_ROWS + src) * C_DIM + lane * 2);
        ax += bf2f(row & 0xffffu) * sc;
        ay += bf2f(row >> 16) * sc;
    }
    float2* po = (float2*)(out + (size_t)d * C_DIM) + lane;
    *po = make_float2(ax, ay);                // full overwrite: no out memset needed
}

// ---------------- fallback gather (single xwb plane, filter by r, RMW out) -----
__global__ void gather_rel_f(const int* __restrict__ dst_off, const int* __restrict__ esrc,
                             const float* __restrict__ inv,
                             const unsigned short* __restrict__ xwb,
                             float* __restrict__ out, int rf) {
    int wave = threadIdx.x >> 6, lane = threadIdx.x & 63;
    int d = blockIdx.x * 4 + wave;
    if (d >= N_NODES) return;
    int o0 = dst_off[d], o1 = dst_off[d + 1];
    float ax = 0.0f, ay = 0.0f;
    bool any = false;
    for (int e = o0; e < o1; ++e) {
        int pk = esrc[e];
        if ((pk >> 17) != rf) continue;
        any = true;
        int src = pk & 0x1ffff;
        unsigned int row = *(const unsigned int*)(xwb + (size_t)src * C_DIM + lane * 2);
        ax += bf2f(row & 0xffffu);
        ay += bf2f(row >> 16);
    }
    if (!any) return;
    float sc = inv[d * R_TYPES + rf];
    float2* po = (float2*)(out + (size_t)d * C_DIM) + lane;
    float2 v = *po;
    v.x += ax * sc;
    v.y += ay * sc;
    *po = v;
}

// ---------------- root GEMM over type-bucketed nodes (fp32) ----------------
#define ASTR 33
#define BSTR 132
__launch_bounds__(256, 2)
__global__ void root_gemm(const float* __restrict__ x, const float* __restrict__ root_w,
                          const float* __restrict__ root_b, const int* __restrict__ tnt,
                          const int* __restrict__ perm, float* __restrict__ out) {
    __shared__ int   pidx[64];
    __shared__ float As[64 * ASTR];
    __shared__ float Bs[32 * BSTR];
    int tid = threadIdx.x;
    if (tid < 64) pidx[tid] = perm[blockIdx.x * 64 + tid];
    __syncthreads();
    if (pidx[0] < 0) return;
    int t = tnt[pidx[0]];
    int tx = tid & 15;
    int ty = tid >> 4;
    float acc[4][8];
    #pragma unroll
    for (int i = 0; i < 4; ++i)
        #pragma unroll
        for (int j = 0; j < 8; ++j) acc[i][j] = 0.0f;

    for (int kb = 0; kb < 4; ++kb) {
        #pragma unroll
        for (int p = 0; p < 2; ++p) {
            int idx = p * 256 + tid;
            int row = idx >> 3;
            int cc  = (idx & 7) * 4;
            int node = pidx[row];
            float4 v = make_float4(0.f, 0.f, 0.f, 0.f);
            if (node >= 0)
                v = *(const float4*)(x + (size_t)node * C_DIM + kb * 32 + cc);
            As[row * ASTR + cc + 0] = v.x;
            As[row * ASTR + cc + 1] = v.y;
            As[row * ASTR + cc + 2] = v.z;
            As[row * ASTR + cc + 3] = v.w;
        }
        #pragma unroll
        for (int p = 0; p < 4; ++p) {
            int idx = p * 256 + tid;
            int o  = idx >> 3;
            int cc = (idx & 7) * 4;
            float4 v = *(const float4*)(root_w + ((size_t)t * 128 + o) * 128 + kb * 32 + cc);
            Bs[(cc + 0) * BSTR + o] = v.x;
            Bs[(cc + 1) * BSTR + o] = v.y;
            Bs[(cc + 2) * BSTR + o] = v.z;
            Bs[(cc + 3) * BSTR + o] = v.w;
        }
        __syncthreads();
        #pragma unroll
        for (int k = 0; k < 32; ++k) {
            float a[4];
            #pragma unroll
            for (int i = 0; i < 4; ++i) a[i] = As[(ty * 4 + i) * ASTR + k];
            float4 b0 = *(const float4*)&Bs[k * BSTR + tx * 4];
            float4 b1 = *(const float4*)&Bs[k * BSTR + 64 + tx * 4];
            float b[8] = {b0.x, b0.y, b0.z, b0.w, b1.x, b1.y, b1.z, b1.w};
            #pragma unroll
            for (int i = 0; i < 4; ++i)
                #pragma unroll
                for (int j = 0; j < 8; ++j) acc[i][j] += a[i] * b[j];
        }
        __syncthreads();
    }
    float4 bias0 = *(const float4*)(root_b + (size_t)t * 128 + tx * 4);
    float4 bias1 = *(const float4*)(root_b + (size_t)t * 128 + 64 + tx * 4);
    #pragma unroll
    for (int i = 0; i < 4; ++i) {
        int node = pidx[ty * 4 + i];
        if (node < 0) continue;
        float* po = out + (size_t)node * C_DIM;
        float4 v0 = *(float4*)(po + tx * 4);
        float4 v1 = *(float4*)(po + 64 + tx * 4);
        v0.x += acc[i][0] + bias0.x;  v0.y += acc[i][1] + bias0.y;
        v0.z += acc[i][2] + bias0.z;  v0.w += acc[i][3] + bias0.w;
        v1.x += acc[i][4] + bias1.x;  v1.y += acc[i][5] + bias1.y;
        v1.z += acc[i][6] + bias1.z;  v1.w += acc[i][7] + bias1.w;
        *(float4*)(po + tx * 4) = v0;
        *(float4*)(po + 64 + tx * 4) = v1;
    }
}

extern "C" void kernel_launch(void* const* d_in, const int* in_sizes, int n_in,
                              void* d_out, int out_size, void* d_ws, size_t ws_size,
                              hipStream_t stream) {
    const float* x      = (const float*)d_in[0];
    const int*   ei     = (const int*)d_in[1];
    const int*   et     = (const int*)d_in[2];
    const int*   tnt    = (const int*)d_in[3];
    const float* rel_w  = (const float*)d_in[4];
    const float* root_w = (const float*)d_in[5];
    const float* root_b = (const float*)d_in[6];
    float* out = (float*)d_out;

    char* ws = (char*)d_ws;
    int*   cnti    = (int*)(ws + OFF_CNTI);
    float* inv     = (float*)(ws + OFF_INV);
    int*   dst_off = (int*)(ws + OFF_DOFF);
    int*   cursor  = (int*)(ws + OFF_CURS);
    int*   misc    = (int*)(ws + OFF_MISC);
    int*   perm    = (int*)(ws + OFF_PERM);
    int*   blk_n   = (int*)(ws + OFF_BLKN);
    int*   bsum    = (int*)(ws + OFF_BSUM);
    int*   esrc    = (int*)(ws + OFF_ESRC);
    unsigned short* xp  = (unsigned short*)(ws + OFF_XP);
    unsigned short* wf  = (unsigned short*)(ws + OFF_WF);
    unsigned short* xwb = (unsigned short*)(ws + OFF_XWB);

    const bool full = (ws_size >= FULL_NEED);   // constant across calls: graph-safe

    hipMemsetAsync(ws + OFF_CNTI, 0, SEGS * sizeof(int), stream);
    hipMemsetAsync(ws + OFF_MISC, 0, 32 * sizeof(int), stream);
    hipMemsetAsync(ws + OFF_PERM, 0xFF, (size_t)PERM_CAP * sizeof(int), stream);
    if (!full)
        hipMemsetAsync(d_out, 0, (size_t)out_size * sizeof(float), stream);

    // dst-CSR sort of edges
    edge_hist  <<<NB_E, 256, 0, stream>>>(ei, et, cnti);
    inv_kernel <<<(SEGS + 255) / 256, 256, 0, stream>>>(cnti, inv);
    dst_scan1  <<<NB_N, 256, 0, stream>>>(cnti, dst_off, bsum);
    seg_scan2  <<<1, 256, 0, stream>>>(bsum, NB_N);
    dst_scan3  <<<NB_N, 256, 0, stream>>>(dst_off, cursor, bsum);
    place_edges<<<NB_E, 256, 0, stream>>>(ei, et, cursor, esrc);

    // node-type buckets for root linear
    node_hist  <<<NB_N, 256, 0, stream>>>(tnt, blk_n);
    scan_blocks<<<T_TYPES, 256, 0, stream>>>(blk_n, NB_N, misc + 0);
    offsets_kernel<<<1, 64, 0, stream>>>(misc);
    node_scatter<<<NB_N, 256, 0, stream>>>(tnt, misc, blk_n, perm);

    // bf16 fragment-layout conversions
    cvt_x_frag<<<(XP_ROWS * 16) / 256, 256, 0, stream>>>(x, xp);
    cvt_w_frag<<<56, 256, 0, stream>>>(rel_w, wf);

    if (full) {
        for (int r = 0; r < R_TYPES; ++r)
            xw_gemm_mfma<<<XP_ROWS / 128, 256, 0, stream>>>(xp, wf, xwb + (size_t)r * XWB_PLANE, r);
        gather_fused<<<(N_NODES + 3) / 4, 256, 0, stream>>>(dst_off, esrc, inv, xwb, out);
    } else {
        for (int r = 0; r < R_TYPES; ++r) {
            xw_gemm_mfma<<<XP_ROWS / 128, 256, 0, stream>>>(xp, wf, xwb, r);
            gather_rel_f<<<(N_NODES + 3) / 4, 256, 0, stream>>>(dst_off, esrc, inv, xwb, out, r);
        }
    }
    root_gemm<<<N_PERM_BLOCKS, 256, 0, stream>>>(x, root_w, root_b, tnt, perm, out);
}

// Round 6
// 537.371 us; speedup vs baseline: 10.2158x; 1.1615x over previous
//
#include <hip/hip_runtime.h>

#define N_NODES 100000
#define N_EDGES 1600000
#define C_DIM   128
#define R_TYPES 7
#define T_TYPES 4
#define SEGS    (N_NODES * R_TYPES)          // 700000 (dst,rel) segments
#define NB_E    (N_EDGES / 256)              // 6250 (E % 256 == 0)
#define NB_N    ((N_NODES + 255) / 256)      // 391 node blocks (also dst-scan blocks)
#define XP_ROWS 100096                       // N padded to 128-row tiles (782 tiles)
#define DST_PART 12500                       // N / 8 (exact)

// ---- workspace layout (bytes) ----
#define OFF_CNTI   0ull                       // int  cnti[SEGS]            2.80 MB
#define OFF_INV    2800000ull                 // f32  inv[SEGS]             2.80 MB
#define OFF_DOFF   5600000ull                 // int  dst_off[N+1]          0.40 MB
#define OFF_CURS   6000004ull                 // int  cursor[N]             0.40 MB
#define OFF_MISC   6400004ull                 // int  misc[32]
#define OFF_PERM   6400132ull                 // int  perm[PERM_CAP]        0.40 MB
#define PERM_CAP   100288
#define N_PERM_BLOCKS 1567
#define OFF_BLKN   6801284ull                 // int  blk_n[NB_N*8]
#define OFF_BSUM   6813796ull                 // int  bsum[NB_N]
#define OFF_ESRC   6815360ull                 // int  esrc[E] packed r<<17|src  6.4 MB
#define OFF_XP     13215360ull                // bf16 xp[XP_ROWS*128] frag     25.6 MB
#define OFF_WF     38839936ull                // bf16 wf[7*128*128] frag        0.23 MB
#define OFF_XWB    39069312ull                // bf16 xwb: full = 7 planes, fallback = 1
#define XWB_PLANE  ((size_t)XP_ROWS * 128)    // elements per relation plane
#define FULL_NEED  218441344ull               // OFF_XWB + 7*25,624,576
#define FB_NEED    64693888ull                // OFF_XWB + 1*25,624,576

typedef __attribute__((ext_vector_type(8))) short short8;
typedef __attribute__((ext_vector_type(4))) float f32x4;

__device__ inline unsigned short f2bf(float f) {
    unsigned int u = __float_as_uint(f);
    u += 0x7fffu + ((u >> 16) & 1u);          // RNE
    return (unsigned short)(u >> 16);
}
__device__ inline float bf2f(unsigned int h) { return __uint_as_float(h << 16); }

// ---------------- per-(dst,rel) counts ----------------
__global__ void edge_hist(const int* __restrict__ ei, const int* __restrict__ et,
                          int* __restrict__ cnti) {
    int e = blockIdx.x * 256 + threadIdx.x;
    atomicAdd(&cnti[ei[N_EDGES + e] * R_TYPES + et[e]], 1);   // 700k addrs: low contention
}

__global__ void inv_kernel(const int* __restrict__ cnti, float* __restrict__ inv) {
    int i = blockIdx.x * blockDim.x + threadIdx.x;
    if (i < SEGS) inv[i] = 1.0f / (float)max(cnti[i], 1);
}

// ---------------- dst-CSR: dst_off = exclusive scan of per-dst degree ----------------
__global__ void dst_scan1(const int* __restrict__ cnti, int* __restrict__ dst_off,
                          int* __restrict__ bsum) {
    __shared__ int sbuf[256];
    int tid = threadIdx.x;
    int i = blockIdx.x * 256 + tid;
    int v = 0;
    if (i < N_NODES) {
        #pragma unroll
        for (int r = 0; r < R_TYPES; ++r) v += cnti[i * R_TYPES + r];
    }
    sbuf[tid] = v;
    __syncthreads();
    #pragma unroll
    for (int off = 1; off < 256; off <<= 1) {
        int t = (tid >= off) ? sbuf[tid - off] : 0;
        __syncthreads();
        sbuf[tid] += t;
        __syncthreads();
    }
    int incl = sbuf[tid];
    if (i < N_NODES) dst_off[i] = incl - v;   // exclusive within chunk
    if (tid == 255) bsum[blockIdx.x] = incl;
}

__global__ void seg_scan2(int* __restrict__ bsum, int nb) {   // 1 block
    __shared__ int sbuf[256];
    int tid = threadIdx.x;
    int running = 0;
    for (int c0 = 0; c0 < nb; c0 += 256) {
        int b = c0 + tid;
        int v = (b < nb) ? bsum[b] : 0;
        sbuf[tid] = v;
        __syncthreads();
        #pragma unroll
        for (int off = 1; off < 256; off <<= 1) {
            int t = (tid >= off) ? sbuf[tid - off] : 0;
            __syncthreads();
            sbuf[tid] += t;
            __syncthreads();
        }
        int incl = sbuf[tid];
        int tot = sbuf[255];
        __syncthreads();
        if (b < nb) bsum[b] = running + incl - v;
        running += tot;
    }
}

__global__ void dst_scan3(int* __restrict__ dst_off, int* __restrict__ cursor,
                          const int* __restrict__ bsum) {
    int i = blockIdx.x * 256 + threadIdx.x;
    if (i < N_NODES) {
        int val = dst_off[i] + bsum[blockIdx.x];
        dst_off[i] = val;
        cursor[i] = val;
    }
    if (i == 0) dst_off[N_NODES] = N_EDGES;
}

// XCD-partitioned placement: block b = chunk (b>>3) x partition (b&7).
// With round-robin blockIdx%8 -> XCD dispatch, each esrc/cursor line is written
// by one XCD only (kills the 16x cross-XCD write amplification seen in R5).
// Correct regardless of the actual mapping: every edge placed exactly once.
__global__ void place_edges(const int* __restrict__ ei, const int* __restrict__ et,
                            int* __restrict__ cursor, int* __restrict__ esrc) {
    int p = blockIdx.x & 7;
    int e = (blockIdx.x >> 3) * 256 + threadIdx.x;
    int d = ei[N_EDGES + e];
    if (d / DST_PART != p) return;
    int pos = atomicAdd(&cursor[d], 1);
    esrc[pos] = (et[e] << 17) | ei[e];        // r in [17:20), src in [0:17)
}

// ---------------- node-type bucketing (for root_gemm) ----------------
__global__ void node_hist(const int* __restrict__ tnt, int* __restrict__ blk_n) {
    __shared__ int h[8];
    int tid = threadIdx.x;
    if (tid < 8) h[tid] = 0;
    __syncthreads();
    int n = blockIdx.x * 256 + tid;
    if (n < N_NODES) atomicAdd(&h[tnt[n]], 1);
    __syncthreads();
    if (tid < T_TYPES) blk_n[blockIdx.x * 8 + tid] = h[tid];
}

__global__ void scan_blocks(int* __restrict__ blk, int nb, int* __restrict__ total) {
    __shared__ int sbuf[256];
    int r = blockIdx.x;
    int tid = threadIdx.x;
    int running = 0;
    for (int c0 = 0; c0 < nb; c0 += 256) {
        int b = c0 + tid;
        int v = (b < nb) ? blk[b * 8 + r] : 0;
        sbuf[tid] = v;
        __syncthreads();
        #pragma unroll
        for (int off = 1; off < 256; off <<= 1) {
            int t = (tid >= off) ? sbuf[tid - off] : 0;
            __syncthreads();
            sbuf[tid] += t;
            __syncthreads();
        }
        int incl = sbuf[tid];
        int chunk_total = sbuf[255];
        __syncthreads();
        if (b < nb) blk[b * 8 + r] = running + incl - v;
        running += chunk_total;
    }
    if (tid == 0) total[r] = running;
}

__global__ void offsets_kernel(int* misc) {
    if (threadIdx.x == 0 && blockIdx.x == 0) {
        int s = 0;
        for (int t = 0; t < T_TYPES; ++t) {
            misc[4 + t] = s;
            s += ((misc[t] + 63) / 64) * 64;
        }
    }
}

__global__ void node_scatter(const int* __restrict__ tnt, const int* __restrict__ misc,
                             const int* __restrict__ blk_n, int* __restrict__ perm) {
    __shared__ int h[8];
    int tid = threadIdx.x;
    if (tid < 8) h[tid] = 0;
    __syncthreads();
    int n = blockIdx.x * 256 + tid;
    if (n < N_NODES) {
        int t = tnt[n];
        int rank = atomicAdd(&h[t], 1);
        perm[misc[4 + t] + blk_n[blockIdx.x * 8 + t] + rank] = n;
    }
}

// ---------------- bf16 fragment-layout conversions ----------------
__global__ void cvt_x_frag(const float* __restrict__ x, unsigned short* __restrict__ xp) {
    int id = blockIdx.x * 256 + threadIdx.x;       // XP_ROWS*16 exact
    int n = id >> 4, ko = id & 15;
    short8 o;
    if (n < N_NODES) {
        const float4* px = (const float4*)(x + (size_t)n * C_DIM + ko * 8);
        float4 a = px[0], b = px[1];
        o[0] = (short)f2bf(a.x); o[1] = (short)f2bf(a.y);
        o[2] = (short)f2bf(a.z); o[3] = (short)f2bf(a.w);
        o[4] = (short)f2bf(b.x); o[5] = (short)f2bf(b.y);
        o[6] = (short)f2bf(b.z); o[7] = (short)f2bf(b.w);
    } else {
        o = (short8)0;
    }
    size_t off = (size_t)(n >> 4) * 2048 + (ko >> 2) * 512 + (ko & 3) * 128 + (n & 15) * 8;
    *(short8*)(xp + off) = o;
}

__global__ void cvt_w_frag(const float* __restrict__ rel_w, unsigned short* __restrict__ wf) {
    int id = blockIdx.x * 256 + threadIdx.x;       // 7*128*16 = 14336 exact
    if (id >= R_TYPES * 128 * 16) return;
    int r = id >> 11, rest = id & 2047;
    int o = rest >> 4, ko = rest & 15;
    const float4* pw = (const float4*)(rel_w + (size_t)r * 16384 + o * 128 + ko * 8);
    float4 a = pw[0], b = pw[1];
    short8 v;
    v[0] = (short)f2bf(a.x); v[1] = (short)f2bf(a.y);
    v[2] = (short)f2bf(a.z); v[3] = (short)f2bf(a.w);
    v[4] = (short)f2bf(b.x); v[5] = (short)f2bf(b.y);
    v[6] = (short)f2bf(b.z); v[7] = (short)f2bf(b.w);
    size_t off = (size_t)r * 16384 + (o >> 4) * 2048 + (ko >> 2) * 512 + (ko & 3) * 128 + (o & 15) * 8;
    *(short8*)(wf + off) = v;
}

// ---------------- fused MFMA GEMM, all 7 relations in one dispatch ----------------
// Block owns 128 rows; A fragments loaded ONCE, reused for all 7 weight sets.
__launch_bounds__(256)
__global__ void xw_gemm_all(const unsigned short* __restrict__ xp,
                            const unsigned short* __restrict__ wf,
                            unsigned short* __restrict__ xwb7) {
    int wave = threadIdx.x >> 6, lane = threadIdx.x & 63;
    int m0 = blockIdx.x * 128;

    short8 a[4][2];
    #pragma unroll
    for (int kb = 0; kb < 4; ++kb)
        #pragma unroll
        for (int rt = 0; rt < 2; ++rt) {
            size_t rtile = (size_t)blockIdx.x * 8 + wave * 2 + rt;
            a[kb][rt] = *(const short8*)(xp + rtile * 2048 + kb * 512 + lane * 8);
        }

    int col = lane & 15, rq = (lane >> 4) * 4;     // C/D: col=lane&15,row=(lane>>4)*4+i
    for (int r = 0; r < R_TYPES; ++r) {
        const unsigned short* wr = wf + (size_t)r * 16384;
        unsigned short* xwb = xwb7 + (size_t)r * XWB_PLANE;
        #pragma unroll
        for (int ct = 0; ct < 8; ++ct) {
            f32x4 acc0 = (f32x4)0.0f, acc1 = (f32x4)0.0f;
            #pragma unroll
            for (int kb = 0; kb < 4; ++kb) {
                short8 b = *(const short8*)(wr + (size_t)ct * 2048 + kb * 512 + lane * 8);
                acc0 = __builtin_amdgcn_mfma_f32_16x16x32_bf16(a[kb][0], b, acc0, 0, 0, 0);
                acc1 = __builtin_amdgcn_mfma_f32_16x16x32_bf16(a[kb][1], b, acc1, 0, 0, 0);
            }
            #pragma unroll
            for (int i = 0; i < 4; ++i) {
                int n0 = m0 + wave * 32 + rq + i;
                if (n0 < N_NODES)
                    xwb[(size_t)n0 * C_DIM + ct * 16 + col] = f2bf(acc0[i]);
                int n1 = n0 + 16;
                if (n1 < N_NODES)
                    xwb[(size_t)n1 * C_DIM + ct * 16 + col] = f2bf(acc1[i]);
            }
        }
    }
}

// fallback per-relation GEMM (single plane)
__launch_bounds__(256)
__global__ void xw_gemm_mfma(const unsigned short* __restrict__ xp,
                             const unsigned short* __restrict__ wf,
                             unsigned short* __restrict__ xwb, int r) {
    int wave = threadIdx.x >> 6, lane = threadIdx.x & 63;
    int m0 = blockIdx.x * 128;
    const unsigned short* wr = wf + (size_t)r * 16384;

    short8 a[4][2];
    #pragma unroll
    for (int kb = 0; kb < 4; ++kb)
        #pragma unroll
        for (int rt = 0; rt < 2; ++rt) {
            size_t rtile = (size_t)blockIdx.x * 8 + wave * 2 + rt;
            a[kb][rt] = *(const short8*)(xp + rtile * 2048 + kb * 512 + lane * 8);
        }

    int col = lane & 15, rq = (lane >> 4) * 4;
    #pragma unroll
    for (int ct = 0; ct < 8; ++ct) {
        f32x4 acc0 = (f32x4)0.0f, acc1 = (f32x4)0.0f;
        #pragma unroll
        for (int kb = 0; kb < 4; ++kb) {
            short8 b = *(const short8*)(wr + (size_t)ct * 2048 + kb * 512 + lane * 8);
            acc0 = __builtin_amdgcn_mfma_f32_16x16x32_bf16(a[kb][0], b, acc0, 0, 0, 0);
            acc1 = __builtin_amdgcn_mfma_f32_16x16x32_bf16(a[kb][1], b, acc1, 0, 0, 0);
        }
        #pragma unroll
        for (int i = 0; i < 4; ++i) {
            int n0 = m0 + wave * 32 + rq + i;
            if (n0 < N_NODES)
                xwb[(size_t)n0 * C_DIM + ct * 16 + col] = f2bf(acc0[i]);
            int n1 = n0 + 16;
            if (n1 < N_NODES)
                xwb[(size_t)n1 * C_DIM + ct * 16 + col] = f2bf(acc1[i]);
        }
    }
}

// ---------------- fused gather: out[d] = sum over d's edges of xwb7[r][src]*inv[d*7+r]
__global__ void gather_fused(const int* __restrict__ dst_off, const int* __restrict__ esrc,
                             const float* __restrict__ inv,
                             const unsigned short* __restrict__ xwb7,
                             float* __restrict__ out) {
    int wave = threadIdx.x >> 6, lane = threadIdx.x & 63;
    int d = blockIdx.x * 4 + wave;
    if (d >= N_NODES) return;
    int o0 = dst_off[d], o1 = dst_off[d + 1];
    float ax = 0.0f, ay = 0.0f;
    int pk_next = (o0 < o1) ? esrc[o0] : 0;
    for (int e = o0; e < o1; ++e) {
        int pk = pk_next;
        if (e + 1 < o1) pk_next = esrc[e + 1];
        int src = pk & 0x1ffff;
        int r   = pk >> 17;
        float sc = inv[d * R_TYPES + r];
        unsigned int row = *(const unsigned int*)(xwb7 + ((size_t)r * XP_ROWS + src) * C_DIM + lane * 2);
        ax += bf2f(row & 0xffffu) * sc;
        ay += bf2f(row >> 16) * sc;
    }
    float2* po = (float2*)(out + (size_t)d * C_DIM) + lane;
    *po = make_float2(ax, ay);                // full overwrite: no out memset needed
}

// ---------------- fallback gather (single xwb plane, filter by r, RMW out) -----
__global__ void gather_rel_f(const int* __restrict__ dst_off, const int* __restrict__ esrc,
                             const float* __restrict__ inv,
                             const unsigned short* __restrict__ xwb,
                             float* __restrict__ out, int rf) {
    int wave = threadIdx.x >> 6, lane = threadIdx.x & 63;
    int d = blockIdx.x * 4 + wave;
    if (d >= N_NODES) return;
    int o0 = dst_off[d], o1 = dst_off[d + 1];
    float ax = 0.0f, ay = 0.0f;
    bool any = false;
    for (int e = o0; e < o1; ++e) {
        int pk = esrc[e];
        if ((pk >> 17) != rf) continue;
        any = true;
        int src = pk & 0x1ffff;
        unsigned int row = *(const unsigned int*)(xwb + (size_t)src * C_DIM + lane * 2);
        ax += bf2f(row & 0xffffu);
        ay += bf2f(row >> 16);
    }
    if (!any) return;
    float sc = inv[d * R_TYPES + rf];
    float2* po = (float2*)(out + (size_t)d * C_DIM) + lane;
    float2 v = *po;
    v.x += ax * sc;
    v.y += ay * sc;
    *po = v;
}

// ---------------- root GEMM over type-bucketed nodes (fp32) ----------------
#define ASTR 33
#define BSTR 132
__launch_bounds__(256, 2)
__global__ void root_gemm(const float* __restrict__ x, const float* __restrict__ root_w,
                          const float* __restrict__ root_b, const int* __restrict__ tnt,
                          const int* __restrict__ perm, float* __restrict__ out) {
    __shared__ int   pidx[64];
    __shared__ float As[64 * ASTR];
    __shared__ float Bs[32 * BSTR];
    int tid = threadIdx.x;
    if (tid < 64) pidx[tid] = perm[blockIdx.x * 64 + tid];
    __syncthreads();
    if (pidx[0] < 0) return;
    int t = tnt[pidx[0]];
    int tx = tid & 15;
    int ty = tid >> 4;
    float acc[4][8];
    #pragma unroll
    for (int i = 0; i < 4; ++i)
        #pragma unroll
        for (int j = 0; j < 8; ++j) acc[i][j] = 0.0f;

    for (int kb = 0; kb < 4; ++kb) {
        #pragma unroll
        for (int p = 0; p < 2; ++p) {
            int idx = p * 256 + tid;
            int row = idx >> 3;
            int cc  = (idx & 7) * 4;
            int node = pidx[row];
            float4 v = make_float4(0.f, 0.f, 0.f, 0.f);
            if (node >= 0)
                v = *(const float4*)(x + (size_t)node * C_DIM + kb * 32 + cc);
            As[row * ASTR + cc + 0] = v.x;
            As[row * ASTR + cc + 1] = v.y;
            As[row * ASTR + cc + 2] = v.z;
            As[row * ASTR + cc + 3] = v.w;
        }
        #pragma unroll
        for (int p = 0; p < 4; ++p) {
            int idx = p * 256 + tid;
            int o  = idx >> 3;
            int cc = (idx & 7) * 4;
            float4 v = *(const float4*)(root_w + ((size_t)t * 128 + o) * 128 + kb * 32 + cc);
            Bs[(cc + 0) * BSTR + o] = v.x;
            Bs[(cc + 1) * BSTR + o] = v.y;
            Bs[(cc + 2) * BSTR + o] = v.z;
            Bs[(cc + 3) * BSTR + o] = v.w;
        }
        __syncthreads();
        #pragma unroll
        for (int k = 0; k < 32; ++k) {
            float a[4];
            #pragma unroll
            for (int i = 0; i < 4; ++i) a[i] = As[(ty * 4 + i) * ASTR + k];
            float4 b0 = *(const float4*)&Bs[k * BSTR + tx * 4];
            float4 b1 = *(const float4*)&Bs[k * BSTR + 64 + tx * 4];
            float b[8] = {b0.x, b0.y, b0.z, b0.w, b1.x, b1.y, b1.z, b1.w};
            #pragma unroll
            for (int i = 0; i < 4; ++i)
                #pragma unroll
                for (int j = 0; j < 8; ++j) acc[i][j] += a[i] * b[j];
        }
        __syncthreads();
    }
    float4 bias0 = *(const float4*)(root_b + (size_t)t * 128 + tx * 4);
    float4 bias1 = *(const float4*)(root_b + (size_t)t * 128 + 64 + tx * 4);
    #pragma unroll
    for (int i = 0; i < 4; ++i) {
        int node = pidx[ty * 4 + i];
        if (node < 0) continue;
        float* po = out + (size_t)node * C_DIM;
        float4 v0 = *(float4*)(po + tx * 4);
        float4 v1 = *(float4*)(po + 64 + tx * 4);
        v0.x += acc[i][0] + bias0.x;  v0.y += acc[i][1] + bias0.y;
        v0.z += acc[i][2] + bias0.z;  v0.w += acc[i][3] + bias0.w;
        v1.x += acc[i][4] + bias1.x;  v1.y += acc[i][5] + bias1.y;
        v1.z += acc[i][6] + bias1.z;  v1.w += acc[i][7] + bias1.w;
        *(float4*)(po + tx * 4) = v0;
        *(float4*)(po + 64 + tx * 4) = v1;
    }
}

extern "C" void kernel_launch(void* const* d_in, const int* in_sizes, int n_in,
                              void* d_out, int out_size, void* d_ws, size_t ws_size,
                              hipStream_t stream) {
    const float* x      = (const float*)d_in[0];
    const int*   ei     = (const int*)d_in[1];
    const int*   et     = (const int*)d_in[2];
    const int*   tnt    = (const int*)d_in[3];
    const float* rel_w  = (const float*)d_in[4];
    const float* root_w = (const float*)d_in[5];
    const float* root_b = (const float*)d_in[6];
    float* out = (float*)d_out;

    char* ws = (char*)d_ws;
    int*   cnti    = (int*)(ws + OFF_CNTI);
    float* inv     = (float*)(ws + OFF_INV);
    int*   dst_off = (int*)(ws + OFF_DOFF);
    int*   cursor  = (int*)(ws + OFF_CURS);
    int*   misc    = (int*)(ws + OFF_MISC);
    int*   perm    = (int*)(ws + OFF_PERM);
    int*   blk_n   = (int*)(ws + OFF_BLKN);
    int*   bsum    = (int*)(ws + OFF_BSUM);
    int*   esrc    = (int*)(ws + OFF_ESRC);
    unsigned short* xp  = (unsigned short*)(ws + OFF_XP);
    unsigned short* wf  = (unsigned short*)(ws + OFF_WF);
    unsigned short* xwb = (unsigned short*)(ws + OFF_XWB);

    const bool full = (ws_size >= FULL_NEED);   // constant across calls: graph-safe

    hipMemsetAsync(ws + OFF_CNTI, 0, SEGS * sizeof(int), stream);
    hipMemsetAsync(ws + OFF_MISC, 0, 32 * sizeof(int), stream);
    hipMemsetAsync(ws + OFF_PERM, 0xFF, (size_t)PERM_CAP * sizeof(int), stream);
    if (!full)
        hipMemsetAsync(d_out, 0, (size_t)out_size * sizeof(float), stream);

    // dst-CSR sort of edges
    edge_hist  <<<NB_E, 256, 0, stream>>>(ei, et, cnti);
    inv_kernel <<<(SEGS + 255) / 256, 256, 0, stream>>>(cnti, inv);
    dst_scan1  <<<NB_N, 256, 0, stream>>>(cnti, dst_off, bsum);
    seg_scan2  <<<1, 256, 0, stream>>>(bsum, NB_N);
    dst_scan3  <<<NB_N, 256, 0, stream>>>(dst_off, cursor, bsum);
    place_edges<<<NB_E * 8, 256, 0, stream>>>(ei, et, cursor, esrc);

    // node-type buckets for root linear
    node_hist  <<<NB_N, 256, 0, stream>>>(tnt, blk_n);
    scan_blocks<<<T_TYPES, 256, 0, stream>>>(blk_n, NB_N, misc + 0);
    offsets_kernel<<<1, 64, 0, stream>>>(misc);
    node_scatter<<<NB_N, 256, 0, stream>>>(tnt, misc, blk_n, perm);

    // bf16 fragment-layout conversions
    cvt_x_frag<<<(XP_ROWS * 16) / 256, 256, 0, stream>>>(x, xp);
    cvt_w_frag<<<56, 256, 0, stream>>>(rel_w, wf);

    if (full) {
        xw_gemm_all <<<XP_ROWS / 128, 256, 0, stream>>>(xp, wf, xwb);
        gather_fused<<<(N_NODES + 3) / 4, 256, 0, stream>>>(dst_off, esrc, inv, xwb, out);
    } else {
        for (int r = 0; r < R_TYPES; ++r) {
            xw_gemm_mfma<<<XP_ROWS / 128, 256, 0, stream>>>(xp, wf, xwb, r);
            gather_rel_f<<<(N_NODES + 3) / 4, 256, 0, stream>>>(dst_off, esrc, inv, xwb, out, r);
        }
    }
    root_gemm<<<N_PERM_BLOCKS, 256, 0, stream>>>(x, root_w, root_b, tnt, perm, out);
}